// Round 3
// baseline (399.147 us; speedup 1.0000x reference)
//
#include <hip/hip_runtime.h>
#include <cmath>

#define NSEQ 256
#define NRES 256
#define CM   256
#define CZ   128
#define NHEAD 8
#define CHD  32
#define NROW 65536   // NSEQ*NRES == NRES*NRES (total m rows)

typedef __attribute__((ext_vector_type(8))) short short8;
typedef __attribute__((ext_vector_type(4))) short s16x4;
typedef __attribute__((ext_vector_type(4))) float f32x4;

// ---- raw bf16 conversion ----
__device__ __forceinline__ unsigned short f2bf(float x) {   // round-nearest-even
    union { float f; unsigned int u; } v; v.f = x;
    unsigned int u = v.u;
    u += 0x7fffu + ((u >> 16) & 1u);
    return (unsigned short)(u >> 16);
}
__device__ __forceinline__ float bf2f(unsigned short b) {
    union { float f; unsigned int u; } v; v.u = ((unsigned int)b) << 16;
    return v.f;
}

// async global->LDS, 16B per lane; LDS dest = uniform base + lane*16
__device__ __forceinline__ void async16(const void* g, void* l) {
    __builtin_amdgcn_global_load_lds(
        (const __attribute__((address_space(1))) unsigned int*)g,
        (__attribute__((address_space(3))) unsigned int*)l, 16, 0, 0);
}

// XCD-aware remap: linear block id b -> XCD b%8. Group the nx column-slabs
// sharing one A m-panel consecutively on the SAME XCD. Bijective when ny%8==0.
__device__ __forceinline__ void xcd_remap(int& x, int& y) {
    const int nx = gridDim.x, ny = gridDim.y;
    const int b = blockIdx.x + blockIdx.y * nx;
    if ((ny & 7) == 0) {
        const int c = b & 7;
        const int t = b >> 3;
        x = t % nx;
        y = c + 8 * (t / nx);
    } else {
        x = blockIdx.x; y = blockIdx.y;
    }
}

// ---------------- LayerNorm over m rows -> single bf16 ----------------
__global__ void __launch_bounds__(64)
ln_m_kernel(const float* __restrict__ m, const float* __restrict__ w,
            const float* __restrict__ b, unsigned short* __restrict__ mbf) {
    const int row = blockIdx.x;
    const int t = threadIdx.x;  // 0..63, one float4 each
    const float* x = m + (size_t)row * CM;
    float4 xv = *(const float4*)(x + t * 4);
    float s  = xv.x + xv.y + xv.z + xv.w;
    float s2 = xv.x * xv.x + xv.y * xv.y + xv.z * xv.z + xv.w * xv.w;
#pragma unroll
    for (int off = 32; off > 0; off >>= 1) {
        s  += __shfl_xor(s, off);
        s2 += __shfl_xor(s2, off);
    }
    const float mu  = s * (1.0f / CM);
    const float var = s2 * (1.0f / CM) - mu * mu;
    const float inv = rsqrtf(var + 1e-5f);
    float4 wv = *(const float4*)(w + t * 4);
    float4 bv = *(const float4*)(b + t * 4);
    ushort4 o4;
    o4.x = f2bf((xv.x - mu) * inv * wv.x + bv.x);
    o4.y = f2bf((xv.y - mu) * inv * wv.y + bv.y);
    o4.z = f2bf((xv.z - mu) * inv * wv.z + bv.z);
    o4.w = f2bf((xv.w - mu) * inv * wv.w + bv.w);
    *(ushort4*)(mbf + (size_t)row * CM + t * 4) = o4;
}

// ---------------- LayerNorm over z rows (128 ch) + pair bias (8 heads) ----------------
__global__ void __launch_bounds__(64)
ln_z_bias_kernel(const float* __restrict__ z, const float* __restrict__ w,
                 const float* __restrict__ b, const float* __restrict__ Wz,
                 float* __restrict__ bias) {
    const int pair = blockIdx.x;  // q*256 + k
    const int t = threadIdx.x;    // 0..63, two floats each
    const float* x = z + (size_t)pair * CZ;
    float2 xv = *(const float2*)(x + t * 2);
    float s  = xv.x + xv.y;
    float s2 = xv.x * xv.x + xv.y * xv.y;
#pragma unroll
    for (int off = 32; off > 0; off >>= 1) {
        s  += __shfl_xor(s, off);
        s2 += __shfl_xor(s2, off);
    }
    const float mu  = s * (1.0f / CZ);
    const float var = s2 * (1.0f / CZ) - mu * mu;
    const float inv = rsqrtf(var + 1e-5f);
    float2 wv = *(const float2*)(w + t * 2);
    float2 bv = *(const float2*)(b + t * 2);
    const float zn0 = (xv.x - mu) * inv * wv.x + bv.x;
    const float zn1 = (xv.y - mu) * inv * wv.y + bv.y;
    float ph[NHEAD];
#pragma unroll
    for (int h = 0; h < NHEAD; h++)
        ph[h] = zn0 * Wz[(2 * t) * NHEAD + h] + zn1 * Wz[(2 * t + 1) * NHEAD + h];
#pragma unroll
    for (int h = 0; h < NHEAD; h++) {
#pragma unroll
        for (int off = 32; off > 0; off >>= 1) ph[h] += __shfl_xor(ph[h], off);
    }
    if (t == 0) {
#pragma unroll
        for (int h = 0; h < NHEAD; h++)
            bias[(size_t)h * NROW + pair] = ph[h];
    }
}

// ---------------- bias transpose: bq[h][q][k] -> bt[h][k][q] (fp32) ----------------
__global__ void __launch_bounds__(256)
bias_tr_kernel(const float* __restrict__ bq, float* __restrict__ bt) {
    __shared__ float tile[32][33];
    const int h = blockIdx.z;
    const int q0 = blockIdx.y * 32, k0 = blockIdx.x * 32;
    const int tr = threadIdx.x >> 5, tc = threadIdx.x & 31;  // 8 rows x 32 cols
#pragma unroll
    for (int i = 0; i < 4; i++)
        tile[tr + i * 8][tc] = bq[(size_t)h * NROW + (size_t)(q0 + tr + i * 8) * 256 + k0 + tc];
    __syncthreads();
#pragma unroll
    for (int i = 0; i < 4; i++)
        bt[(size_t)h * NROW + (size_t)(k0 + tr + i * 8) * 256 + q0 + tc] = tile[tc][tr + i * 8];
}

// ---------------- weight transpose: Wq/Wk/Wv/Wg -> single bf16, Wo -> hi/lo ----------------
__global__ void __launch_bounds__(256)
wsplit_kernel(const float* __restrict__ Wq, const float* __restrict__ Wk,
              const float* __restrict__ Wv, const float* __restrict__ Wg,
              const float* __restrict__ Wo, unsigned short* __restrict__ wbf) {
    const int n = blockIdx.x;        // output row (col of W)
    const int mat = blockIdx.y;      // 0..4
    const int k = threadIdx.x;       // 0..255
    const float* W = (mat == 0) ? Wq : (mat == 1) ? Wk : (mat == 2) ? Wv
                   : (mat == 3) ? Wg : Wo;
    const float v = W[(size_t)k * 256 + n];
    unsigned short h = f2bf(v);
    unsigned short* hi = wbf + (size_t)mat * 65536;
    hi[(size_t)n * 256 + k] = h;
    if (mat == 4) {
        unsigned short* lo = wbf + (size_t)5 * 65536;
        lo[(size_t)n * 256 + k] = f2bf(v - bf2f(h));
    }
}

// ---------------- single-pass bf16 MFMA GEMM: C[128,128] tile, K=256, bf16 out ----------------
__device__ __forceinline__ void gemm128_1p(
    const unsigned short* __restrict__ A_g, const unsigned short* __restrict__ Bt_g,
    int m0, int n0, short* A_s, short* B_s,
    unsigned short* __restrict__ C, const float* __restrict__ bias,
    float alpha, int act) {
    const int tid  = threadIdx.x;
    const int wid  = tid >> 6;
    const int lane = tid & 63;
    const int wm = (wid >> 1) * 64;
    const int wn = (wid & 1) * 64;

    f32x4 acc[4][4];
#pragma unroll
    for (int i = 0; i < 4; i++)
#pragma unroll
        for (int j = 0; j < 4; j++) acc[i][j] = (f32x4){0.f, 0.f, 0.f, 0.f};

    const unsigned short* gmat = (wid < 2) ? A_g : Bt_g;
    short* lmat = (wid < 2) ? A_s : B_s;
    const int brow = (wid < 2) ? m0 : n0;
    const int half = (wid & 1) * 64;
    const int srow = lane >> 2;
    const int skq  = (lane & 3) * 8;

    const int lrow = lane & 15;
    const int lk   = (lane >> 4) * 8;

    for (int k0 = 0; k0 < 256; k0 += 32) {
#pragma unroll
        for (int r = 0; r < 4; r++) {
            const unsigned short* g = gmat + (size_t)(brow + half + r * 16 + srow) * 256 + k0 + skq;
            short* l = lmat + (half + r * 16) * 32;
            async16(g, l);
        }
        __syncthreads();

        short8 ah[4], bh[4];
#pragma unroll
        for (int f = 0; f < 4; f++) {
            ah[f] = *(const short8*)&A_s[(wm + f * 16 + lrow) * 32 + lk];
            bh[f] = *(const short8*)&B_s[(wn + f * 16 + lrow) * 32 + lk];
        }
#pragma unroll
        for (int i = 0; i < 4; i++)
#pragma unroll
            for (int j = 0; j < 4; j++)
                acc[i][j] = __builtin_amdgcn_mfma_f32_16x16x32_bf16(ah[i], bh[j], acc[i][j], 0, 0, 0);
        __syncthreads();
    }

    const int ccol0 = lane & 15;
    const int crow0 = (lane >> 4) * 4;
    float bvv[4];
#pragma unroll
    for (int j = 0; j < 4; j++)
        bvv[j] = bias ? bias[n0 + wn + j * 16 + ccol0] : 0.0f;
#pragma unroll
    for (int i = 0; i < 4; i++) {
#pragma unroll
        for (int r = 0; r < 4; r++) {
            const int row = m0 + wm + i * 16 + crow0 + r;
#pragma unroll
            for (int j = 0; j < 4; j++) {
                const int col = n0 + wn + j * 16 + ccol0;
                float v = acc[i][j][r] * alpha + bvv[j];
                if (act == 1) v = 1.0f / (1.0f + __expf(-v));
                C[(size_t)row * 256 + col] = f2bf(v);
            }
        }
    }
}

// fused Q/K/V/G projection (single-pass bf16, bf16 out)
__global__ void __launch_bounds__(256)
gemm_qkvg_kernel(const unsigned short* __restrict__ A,
                 const unsigned short* __restrict__ wbf,
                 unsigned short* __restrict__ qb, unsigned short* __restrict__ kb,
                 unsigned short* __restrict__ vb, unsigned short* __restrict__ gb,
                 const float* __restrict__ bg, float scale) {
    __shared__ short A_s[128 * 32];
    __shared__ short B_s[128 * 32];
    int bx, by;
    xcd_remap(bx, by);
    const int which = bx >> 1;
    const int n0 = (bx & 1) * 128;
    const int m0 = by * 128;
    const unsigned short* bt = wbf + (size_t)which * 65536;
    unsigned short* C = (which == 0) ? qb : (which == 1) ? kb : (which == 2) ? vb : gb;
    const float alpha = (which == 0) ? scale : 1.0f;
    const float* bias = (which == 3) ? bg : nullptr;
    const int act = (which == 3) ? 1 : 0;
    gemm128_1p(A, bt, m0, n0, A_s, B_s, C, bias, alpha, act);
}

// output projection: C = (g*o) @ Wo + bo. A = packed u32 (hi<<16|lo), B = Wo hi/lo.
__global__ void __launch_bounds__(256)
gemm_out_kernel(const unsigned int* __restrict__ Ap_g,
                const unsigned short* __restrict__ wbf, float* __restrict__ C,
                const float* __restrict__ bo) {
    __shared__ unsigned int Ap_s[128 * 32];  // 16 KB
    __shared__ short Bhi_s[128 * 32];        // 8 KB
    __shared__ short Blo_s[128 * 32];        // 8 KB
    int bx, by;
    xcd_remap(bx, by);
    const int m0 = by * 128, n0 = bx * 128;
    const unsigned short* Bthi_g = wbf + (size_t)4 * 65536;
    const unsigned short* Btlo_g = wbf + (size_t)5 * 65536;

    const int tid  = threadIdx.x;
    const int wid  = tid >> 6;
    const int lane = tid & 63;
    const int wm = (wid >> 1) * 64;
    const int wn = (wid & 1) * 64;

    f32x4 acc[4][4];
#pragma unroll
    for (int i = 0; i < 4; i++)
#pragma unroll
        for (int j = 0; j < 4; j++) acc[i][j] = (f32x4){0.f, 0.f, 0.f, 0.f};

    const int lrow = lane & 15;
    const int lk   = (lane >> 4) * 8;

    for (int k0 = 0; k0 < 256; k0 += 32) {
        if (wid < 2) {
            // A packed: rows (wid*64 .. +63), 32 u32/row; 8 rows per instr
            const int half = wid * 64;
            const int srow = lane >> 3;          // 0..7
            const int scol = (lane & 7) * 4;     // u32 idx within row
#pragma unroll
            for (int r = 0; r < 8; r++) {
                const unsigned int* g = Ap_g + (size_t)(m0 + half + r * 8 + srow) * 256 + k0 + scol;
                unsigned int* l = Ap_s + (half + r * 8) * 32;
                async16(g, l);
            }
        } else {
            const unsigned short* gmat = (wid == 2) ? Bthi_g : Btlo_g;
            short* lmat = (wid == 2) ? Bhi_s : Blo_s;
            const int srow = lane >> 2;
            const int skq  = (lane & 3) * 8;
#pragma unroll
            for (int r = 0; r < 8; r++) {
                const unsigned short* g = gmat + (size_t)(n0 + r * 16 + srow) * 256 + k0 + skq;
                short* l = lmat + (r * 16) * 32;
                async16(g, l);
            }
        }
        __syncthreads();

        short8 ah[4], al[4], bh[4], bl[4];
#pragma unroll
        for (int f = 0; f < 4; f++) {
            const uint4* ap = (const uint4*)&Ap_s[(wm + f * 16 + lrow) * 32 + lk];
            uint4 a0 = ap[0], a1 = ap[1];
            union { unsigned int u[4]; short8 s; } uh, ul;
            uh.u[0] = __builtin_amdgcn_perm(a0.y, a0.x, 0x07060302u);
            uh.u[1] = __builtin_amdgcn_perm(a0.w, a0.z, 0x07060302u);
            uh.u[2] = __builtin_amdgcn_perm(a1.y, a1.x, 0x07060302u);
            uh.u[3] = __builtin_amdgcn_perm(a1.w, a1.z, 0x07060302u);
            ul.u[0] = __builtin_amdgcn_perm(a0.y, a0.x, 0x05040100u);
            ul.u[1] = __builtin_amdgcn_perm(a0.w, a0.z, 0x05040100u);
            ul.u[2] = __builtin_amdgcn_perm(a1.y, a1.x, 0x05040100u);
            ul.u[3] = __builtin_amdgcn_perm(a1.w, a1.z, 0x05040100u);
            ah[f] = uh.s; al[f] = ul.s;
            bh[f] = *(const short8*)&Bhi_s[(wn + f * 16 + lrow) * 32 + lk];
            bl[f] = *(const short8*)&Blo_s[(wn + f * 16 + lrow) * 32 + lk];
        }
#pragma unroll
        for (int i = 0; i < 4; i++)
#pragma unroll
            for (int j = 0; j < 4; j++) {
                acc[i][j] = __builtin_amdgcn_mfma_f32_16x16x32_bf16(ah[i], bh[j], acc[i][j], 0, 0, 0);
                acc[i][j] = __builtin_amdgcn_mfma_f32_16x16x32_bf16(ah[i], bl[j], acc[i][j], 0, 0, 0);
                acc[i][j] = __builtin_amdgcn_mfma_f32_16x16x32_bf16(al[i], bh[j], acc[i][j], 0, 0, 0);
            }
        __syncthreads();
    }

    const int ccol0 = lane & 15;
    const int crow0 = (lane >> 4) * 4;
    float bvv[4];
#pragma unroll
    for (int j = 0; j < 4; j++)
        bvv[j] = bo[n0 + wn + j * 16 + ccol0];
#pragma unroll
    for (int i = 0; i < 4; i++) {
#pragma unroll
        for (int r = 0; r < 4; r++) {
            const int row = m0 + wm + i * 16 + crow0 + r;
#pragma unroll
            for (int j = 0; j < 4; j++) {
                const int col = n0 + wn + j * 16 + ccol0;
                C[(size_t)row * 256 + col] = acc[i][j][r] + bvv[j];
            }
        }
    }
}

// ---------------- MFMA attention: block=(s,h), 4 waves x 64 q-rows ----------------
// S^T = K·Q^T per 32-key chunk; its C-layout (4 consecutive kk per lane at lg*4)
// feeds v_mfma_f32_16x16x16_bf16 A-frags DIRECTLY -> no Ps LDS round-trip.
// LDS 38.7 KB -> 4 blocks/CU. Bias transposed [h][k][q] -> coalesced loads.
// Output packed u32 (hi<<16|lo) -> full 128B lines per (row,head).
__global__ void __launch_bounds__(256, 4)
attn_mfma_kernel(const unsigned short* __restrict__ q, const unsigned short* __restrict__ k,
                 const unsigned short* __restrict__ v, const float* __restrict__ bias_t,
                 const unsigned short* __restrict__ g,
                 unsigned int* __restrict__ opack) {
    const int s = blockIdx.x, h = blockIdx.y;
    __shared__ short Ks[256][40];    // K bf16 [kk][c]            20480 B
    __shared__ short Vs[32][268];    // V^T bf16 [c][kk], pad 268 17152 B
    __shared__ float li_s[4][64];    //                             1024 B  => 38656 B
    const int tid = threadIdx.x;
    const int w = tid >> 6, l = tid & 63;
    const int lg = l >> 4, l15 = l & 15;
    const size_t sbase = (size_t)s * (NRES * CM);

    // ---- stage K (row-major) and V (transposed), already bf16 ----
    {
        const int kk0 = tid >> 2;          // 0..63
        const int c8 = (tid & 3) * 8;      // 0,8,16,24
#pragma unroll
        for (int r4 = 0; r4 < 4; r4++) {
            const int kk = r4 * 64 + kk0;
            const size_t gi = sbase + (size_t)kk * CM + h * CHD + c8;
            short8 k8 = *(const short8*)(k + gi);
            short8 v8 = *(const short8*)(v + gi);
            *(short8*)&Ks[kk][c8] = k8;
#pragma unroll
            for (int jj = 0; jj < 8; jj++) Vs[c8 + jj][kk] = v8[jj];
        }
    }
    // ---- Q fragments straight from global bf16 (B-operand: col=l15, k=lg*8..+8) ----
    const int wq0 = w * 64;
    short8 qf[4];
#pragma unroll
    for (int mq = 0; mq < 4; mq++)
        qf[mq] = *(const short8*)(q + sbase + (size_t)(wq0 + mq * 16 + l15) * CM + h * CHD + lg * 8);
    __syncthreads();

    f32x4 acco[4][2];
#pragma unroll
    for (int mq = 0; mq < 4; mq++)
#pragma unroll
        for (int nc = 0; nc < 2; nc++) acco[mq][nc] = (f32x4){0.f, 0.f, 0.f, 0.f};
    float lip[4] = {0.f, 0.f, 0.f, 0.f};
    const float* bt = bias_t + (size_t)h * NROW;

    for (int ch = 0; ch < 8; ch++) {
        const int kb = ch * 32;
        short8 kf[2];
#pragma unroll
        for (int ik = 0; ik < 2; ik++)
            kf[ik] = *(const short8*)&Ks[kb + ik * 16 + l15][lg * 8];
#pragma unroll
        for (int ik = 0; ik < 2; ik++) {
            // V fragments for this 16-key slice (B-frag of 16x16x16: col=l15, k=lg*4..+3)
            s16x4 vf[2];
#pragma unroll
            for (int nc = 0; nc < 2; nc++)
                vf[nc] = *(const s16x4*)&Vs[nc * 16 + l15][kb + ik * 16 + lg * 4];
            const int kk0a = kb + ik * 16 + lg * 4;   // absolute kk of reg 0
#pragma unroll
            for (int jq = 0; jq < 4; jq++) {
                const int qrow = wq0 + jq * 16 + l15;
                f32x4 sa = (f32x4){0.f, 0.f, 0.f, 0.f};
                sa = __builtin_amdgcn_mfma_f32_16x16x32_bf16(kf[ik], qf[jq], sa, 0, 0, 0);
                // bias_t[h][kk][q]: lanes l15 -> consecutive q, coalesced
                const float b0 = bt[(size_t)(kk0a + 0) * 256 + qrow];
                const float b1 = bt[(size_t)(kk0a + 1) * 256 + qrow];
                const float b2 = bt[(size_t)(kk0a + 2) * 256 + qrow];
                const float b3 = bt[(size_t)(kk0a + 3) * 256 + qrow];
                const float p0 = __expf(sa[0] + b0);
                const float p1 = __expf(sa[1] + b1);
                const float p2 = __expf(sa[2] + b2);
                const float p3 = __expf(sa[3] + b3);
                lip[jq] += (p0 + p1) + (p2 + p3);
                s16x4 pa;
                pa[0] = (short)f2bf(p0); pa[1] = (short)f2bf(p1);
                pa[2] = (short)f2bf(p2); pa[3] = (short)f2bf(p3);
                // P (C-layout of S^T) IS the 16x16x16 A-frag: row=l15, k=lg*4+j
#pragma unroll
                for (int nc = 0; nc < 2; nc++)
                    acco[jq][nc] = __builtin_amdgcn_mfma_f32_16x16x16bf16_1k(
                        pa, vf[nc], acco[jq][nc], 0, 0, 0);
            }
        }
    }

    // ---- row-sum reduction across lane groups; remap via tiny LDS ----
#pragma unroll
    for (int jq = 0; jq < 4; jq++) {
        lip[jq] += __shfl_xor(lip[jq], 16);
        lip[jq] += __shfl_xor(lip[jq], 32);
        li_s[w][jq * 16 + l15] = lip[jq];
    }

    // ---- epilogue: O/li * g, bf16 hi/lo packed into one u32 store ----
#pragma unroll
    for (int mq = 0; mq < 4; mq++) {
#pragma unroll
        for (int r = 0; r < 4; r++) {
            const int qrow = wq0 + mq * 16 + lg * 4 + r;
            const float inv = 1.0f / li_s[w][mq * 16 + lg * 4 + r];
            const size_t rb = sbase + (size_t)qrow * CM + h * CHD;
#pragma unroll
            for (int nc = 0; nc < 2; nc++) {
                const int c = nc * 16 + l15;
                const float val = acco[mq][nc][r] * inv * bf2f(g[rb + c]);
                const unsigned short hi = f2bf(val);
                const unsigned short lo = f2bf(val - bf2f(hi));
                opack[rb + c] = ((unsigned int)hi << 16) | lo;
            }
        }
    }
}

extern "C" void kernel_launch(void* const* d_in, const int* in_sizes, int n_in,
                              void* d_out, int out_size, void* d_ws, size_t ws_size,
                              hipStream_t stream) {
    const float* m    = (const float*)d_in[0];
    const float* z    = (const float*)d_in[1];
    const float* lnmw = (const float*)d_in[2];
    const float* lnmb = (const float*)d_in[3];
    const float* lnzw = (const float*)d_in[4];
    const float* lnzb = (const float*)d_in[5];
    const float* Wz   = (const float*)d_in[6];
    const float* Wq   = (const float*)d_in[7];
    const float* Wk   = (const float*)d_in[8];
    const float* Wv   = (const float*)d_in[9];
    const float* Wg   = (const float*)d_in[10];
    const float* bg   = (const float*)d_in[11];
    const float* Wo   = (const float*)d_in[12];
    const float* bo   = (const float*)d_in[13];
    float* out = (float*)d_out;

    char* wsb = (char*)d_ws;
    const size_t BIASB = (size_t)NHEAD * NROW * 4;   // 2 MB each
    const size_t WBFB  = (size_t)6 * 65536 * 2;      // 768 KB
    float* bias_qk = (float*)wsb;
    float* bias_t  = (float*)(wsb + BIASB);
    unsigned short* wbf = (unsigned short*)(wsb + 2 * BIASB);
    char* chunk0 = wsb + 2 * BIASB + ((WBFB + 255) & ~(size_t)255);

    // Per-s-elem: q,k,v,g,mbf bf16 (10 B) + opack u32 (4 B) = 14 B
    const size_t avail = ws_size - (size_t)(chunk0 - wsb);
    int SC = NSEQ;
    while (SC > 1 && (size_t)SC * NRES * CM * 14 > avail) SC >>= 1;
    const size_t CHE = (size_t)SC * NRES * CM;

    unsigned short* qb  = (unsigned short*)chunk0;
    unsigned short* kb  = qb + CHE;
    unsigned short* vb  = kb + CHE;
    unsigned short* gb  = vb + CHE;
    unsigned short* mbf = gb + CHE;
    unsigned int* opk   = (unsigned int*)(mbf + CHE);

    ln_z_bias_kernel<<<NROW, 64, 0, stream>>>(z, lnzw, lnzb, Wz, bias_qk);
    bias_tr_kernel<<<dim3(8, 8, 8), 256, 0, stream>>>(bias_qk, bias_t);
    wsplit_kernel<<<dim3(256, 5), 256, 0, stream>>>(Wq, Wk, Wv, Wg, Wo, wbf);

    const int rows = SC * NRES;
    const int mtiles = rows / 128;
    const float scale = 0.17677669529663687f;  // 1/sqrt(32), folded into q

    for (int s0 = 0; s0 < NSEQ; s0 += SC) {
        const float* m_c   = m   + (size_t)s0 * NRES * CM;
        float*       out_c = out + (size_t)s0 * NRES * CM;

        ln_m_kernel<<<rows, 64, 0, stream>>>(m_c, lnmw, lnmb, mbf);

        gemm_qkvg_kernel<<<dim3(8, mtiles), 256, 0, stream>>>(
            mbf, wbf, qb, kb, vb, gb, bg, scale);

        attn_mfma_kernel<<<dim3(SC, NHEAD), 256, 0, stream>>>(
            qb, kb, vb, bias_t, gb, opk);

        gemm_out_kernel<<<dim3(2, mtiles), 256, 0, stream>>>(
            opk, wbf, out_c, bo);
    }
}

// Round 4
// 373.107 us; speedup vs baseline: 1.0698x; 1.0698x over previous
//
#include <hip/hip_runtime.h>
#include <cmath>

#define NSEQ 256
#define NRES 256
#define CM   256
#define CZ   128
#define NHEAD 8
#define CHD  32
#define NROW 65536   // NSEQ*NRES == NRES*NRES (total m rows)

typedef __attribute__((ext_vector_type(8))) short short8;
typedef __attribute__((ext_vector_type(4))) short s16x4;
typedef __attribute__((ext_vector_type(4))) float f32x4;

// ---- raw bf16 conversion ----
__device__ __forceinline__ unsigned short f2bf(float x) {   // round-nearest-even
    union { float f; unsigned int u; } v; v.f = x;
    unsigned int u = v.u;
    u += 0x7fffu + ((u >> 16) & 1u);
    return (unsigned short)(u >> 16);
}
__device__ __forceinline__ float bf2f(unsigned short b) {
    union { float f; unsigned int u; } v; v.u = ((unsigned int)b) << 16;
    return v.f;
}

// async global->LDS, 16B per lane; LDS dest = uniform base + lane*16
__device__ __forceinline__ void async16(const void* g, void* l) {
    __builtin_amdgcn_global_load_lds(
        (const __attribute__((address_space(1))) unsigned int*)g,
        (__attribute__((address_space(3))) unsigned int*)l, 16, 0, 0);
}

// XCD-aware remap: linear block id b -> XCD b%8. Group the nx column-slabs
// sharing one A m-panel consecutively on the SAME XCD. Bijective when ny%8==0.
__device__ __forceinline__ void xcd_remap(int& x, int& y) {
    const int nx = gridDim.x, ny = gridDim.y;
    const int b = blockIdx.x + blockIdx.y * nx;
    if ((ny & 7) == 0) {
        const int c = b & 7;
        const int t = b >> 3;
        x = t % nx;
        y = c + 8 * (t / nx);
    } else {
        x = blockIdx.x; y = blockIdx.y;
    }
}

// ---------------- LayerNorm over m rows -> single bf16 ----------------
__global__ void __launch_bounds__(64)
ln_m_kernel(const float* __restrict__ m, const float* __restrict__ w,
            const float* __restrict__ b, unsigned short* __restrict__ mbf) {
    const int row = blockIdx.x;
    const int t = threadIdx.x;  // 0..63, one float4 each
    const float* x = m + (size_t)row * CM;
    float4 xv = *(const float4*)(x + t * 4);
    float s  = xv.x + xv.y + xv.z + xv.w;
    float s2 = xv.x * xv.x + xv.y * xv.y + xv.z * xv.z + xv.w * xv.w;
#pragma unroll
    for (int off = 32; off > 0; off >>= 1) {
        s  += __shfl_xor(s, off);
        s2 += __shfl_xor(s2, off);
    }
    const float mu  = s * (1.0f / CM);
    const float var = s2 * (1.0f / CM) - mu * mu;
    const float inv = rsqrtf(var + 1e-5f);
    float4 wv = *(const float4*)(w + t * 4);
    float4 bv = *(const float4*)(b + t * 4);
    ushort4 o4;
    o4.x = f2bf((xv.x - mu) * inv * wv.x + bv.x);
    o4.y = f2bf((xv.y - mu) * inv * wv.y + bv.y);
    o4.z = f2bf((xv.z - mu) * inv * wv.z + bv.z);
    o4.w = f2bf((xv.w - mu) * inv * wv.w + bv.w);
    *(ushort4*)(mbf + (size_t)row * CM + t * 4) = o4;
}

// ---------------- LayerNorm over z rows + pair bias; bias pre-scaled by log2(e) ----------------
__global__ void __launch_bounds__(64)
ln_z_bias_kernel(const float* __restrict__ z, const float* __restrict__ w,
                 const float* __restrict__ b, const float* __restrict__ Wz,
                 float* __restrict__ bias) {
    const int pair = blockIdx.x;  // q*256 + k
    const int t = threadIdx.x;    // 0..63, two floats each
    const float* x = z + (size_t)pair * CZ;
    float2 xv = *(const float2*)(x + t * 2);
    float s  = xv.x + xv.y;
    float s2 = xv.x * xv.x + xv.y * xv.y;
#pragma unroll
    for (int off = 32; off > 0; off >>= 1) {
        s  += __shfl_xor(s, off);
        s2 += __shfl_xor(s2, off);
    }
    const float mu  = s * (1.0f / CZ);
    const float var = s2 * (1.0f / CZ) - mu * mu;
    const float inv = rsqrtf(var + 1e-5f);
    float2 wv = *(const float2*)(w + t * 2);
    float2 bv = *(const float2*)(b + t * 2);
    const float zn0 = (xv.x - mu) * inv * wv.x + bv.x;
    const float zn1 = (xv.y - mu) * inv * wv.y + bv.y;
    float ph[NHEAD];
#pragma unroll
    for (int h = 0; h < NHEAD; h++)
        ph[h] = zn0 * Wz[(2 * t) * NHEAD + h] + zn1 * Wz[(2 * t + 1) * NHEAD + h];
#pragma unroll
    for (int h = 0; h < NHEAD; h++) {
#pragma unroll
        for (int off = 32; off > 0; off >>= 1) ph[h] += __shfl_xor(ph[h], off);
    }
    if (t == 0) {
#pragma unroll
        for (int h = 0; h < NHEAD; h++)
            bias[(size_t)h * NROW + pair] = ph[h] * 1.4426950408889634f;  // log2(e) folded
    }
}

// ---------------- weight transpose: Wq/Wk/Wv/Wg -> single bf16, Wo -> hi/lo ----------------
__global__ void __launch_bounds__(256)
wsplit_kernel(const float* __restrict__ Wq, const float* __restrict__ Wk,
              const float* __restrict__ Wv, const float* __restrict__ Wg,
              const float* __restrict__ Wo, unsigned short* __restrict__ wbf) {
    const int n = blockIdx.x;        // output row (col of W)
    const int mat = blockIdx.y;      // 0..4
    const int k = threadIdx.x;       // 0..255
    const float* W = (mat == 0) ? Wq : (mat == 1) ? Wk : (mat == 2) ? Wv
                   : (mat == 3) ? Wg : Wo;
    const float v = W[(size_t)k * 256 + n];
    unsigned short h = f2bf(v);
    unsigned short* hi = wbf + (size_t)mat * 65536;
    hi[(size_t)n * 256 + k] = h;
    if (mat == 4) {
        unsigned short* lo = wbf + (size_t)5 * 65536;
        lo[(size_t)n * 256 + k] = f2bf(v - bf2f(h));
    }
}

// ---------------- single-pass bf16 MFMA GEMM: C[128,128] tile, K=256 ----------------
// Output stored HEAD-MAJOR: C[(col>>5)*rowsTot + row][col&31] (bf16).
__device__ __forceinline__ void gemm128_1p(
    const unsigned short* __restrict__ A_g, const unsigned short* __restrict__ Bt_g,
    int m0, int n0, int rowsTot, short* A_s, short* B_s,
    unsigned short* __restrict__ C, const float* __restrict__ bias,
    float alpha, int act) {
    const int tid  = threadIdx.x;
    const int wid  = tid >> 6;
    const int lane = tid & 63;
    const int wm = (wid >> 1) * 64;
    const int wn = (wid & 1) * 64;

    f32x4 acc[4][4];
#pragma unroll
    for (int i = 0; i < 4; i++)
#pragma unroll
        for (int j = 0; j < 4; j++) acc[i][j] = (f32x4){0.f, 0.f, 0.f, 0.f};

    const unsigned short* gmat = (wid < 2) ? A_g : Bt_g;
    short* lmat = (wid < 2) ? A_s : B_s;
    const int brow = (wid < 2) ? m0 : n0;
    const int half = (wid & 1) * 64;
    const int srow = lane >> 2;
    const int skq  = (lane & 3) * 8;

    const int lrow = lane & 15;
    const int lk   = (lane >> 4) * 8;

    for (int k0 = 0; k0 < 256; k0 += 32) {
#pragma unroll
        for (int r = 0; r < 4; r++) {
            const unsigned short* g = gmat + (size_t)(brow + half + r * 16 + srow) * 256 + k0 + skq;
            short* l = lmat + (half + r * 16) * 32;
            async16(g, l);
        }
        __syncthreads();

        short8 ah[4], bh[4];
#pragma unroll
        for (int f = 0; f < 4; f++) {
            ah[f] = *(const short8*)&A_s[(wm + f * 16 + lrow) * 32 + lk];
            bh[f] = *(const short8*)&B_s[(wn + f * 16 + lrow) * 32 + lk];
        }
#pragma unroll
        for (int i = 0; i < 4; i++)
#pragma unroll
            for (int j = 0; j < 4; j++)
                acc[i][j] = __builtin_amdgcn_mfma_f32_16x16x32_bf16(ah[i], bh[j], acc[i][j], 0, 0, 0);
        __syncthreads();
    }

    const int ccol0 = lane & 15;
    const int crow0 = (lane >> 4) * 4;
    float bvv[4];
#pragma unroll
    for (int j = 0; j < 4; j++)
        bvv[j] = bias ? bias[n0 + wn + j * 16 + ccol0] : 0.0f;
#pragma unroll
    for (int i = 0; i < 4; i++) {
#pragma unroll
        for (int r = 0; r < 4; r++) {
            const int row = m0 + wm + i * 16 + crow0 + r;
#pragma unroll
            for (int j = 0; j < 4; j++) {
                const int col = n0 + wn + j * 16 + ccol0;
                float v = acc[i][j][r] * alpha + bvv[j];
                if (act == 1) v = 1.0f / (1.0f + __expf(-v));
                C[((size_t)(col >> 5) * rowsTot + row) * 32 + (col & 31)] = f2bf(v);
            }
        }
    }
}

// fused Q/K/V/G projection (single-pass bf16, head-major bf16 out)
__global__ void __launch_bounds__(256)
gemm_qkvg_kernel(const unsigned short* __restrict__ A,
                 const unsigned short* __restrict__ wbf,
                 unsigned short* __restrict__ qb, unsigned short* __restrict__ kb,
                 unsigned short* __restrict__ vb, unsigned short* __restrict__ gb,
                 const float* __restrict__ bg, float scale, int rowsTot) {
    __shared__ short A_s[128 * 32];
    __shared__ short B_s[128 * 32];
    int bx, by;
    xcd_remap(bx, by);
    const int which = bx >> 1;
    const int n0 = (bx & 1) * 128;
    const int m0 = by * 128;
    const unsigned short* bt = wbf + (size_t)which * 65536;
    unsigned short* C = (which == 0) ? qb : (which == 1) ? kb : (which == 2) ? vb : gb;
    const float alpha = (which == 0) ? scale : 1.0f;
    const float* bias = (which == 3) ? bg : nullptr;
    const int act = (which == 3) ? 1 : 0;
    gemm128_1p(A, bt, m0, n0, rowsTot, A_s, B_s, C, bias, alpha, act);
}

// output projection: C = (g*o) @ Wo + bo. A = packed u32 (hi<<16|lo) HEAD-MAJOR.
__global__ void __launch_bounds__(256)
gemm_out_kernel(const unsigned int* __restrict__ Ap_g,
                const unsigned short* __restrict__ wbf, float* __restrict__ C,
                const float* __restrict__ bo, int rowsTot) {
    __shared__ unsigned int Ap_s[128 * 32];  // 16 KB
    __shared__ short Bhi_s[128 * 32];        // 8 KB
    __shared__ short Blo_s[128 * 32];        // 8 KB
    int bx, by;
    xcd_remap(bx, by);
    const int m0 = by * 128, n0 = bx * 128;
    const unsigned short* Bthi_g = wbf + (size_t)4 * 65536;
    const unsigned short* Btlo_g = wbf + (size_t)5 * 65536;

    const int tid  = threadIdx.x;
    const int wid  = tid >> 6;
    const int lane = tid & 63;
    const int wm = (wid >> 1) * 64;
    const int wn = (wid & 1) * 64;

    f32x4 acc[4][4];
#pragma unroll
    for (int i = 0; i < 4; i++)
#pragma unroll
        for (int j = 0; j < 4; j++) acc[i][j] = (f32x4){0.f, 0.f, 0.f, 0.f};

    const int lrow = lane & 15;
    const int lk   = (lane >> 4) * 8;

    for (int k0 = 0; k0 < 256; k0 += 32) {
        if (wid < 2) {
            // A head-major: k0 block == head plane (k0>>5); rows of 32 u32 = 128B
            const int half = wid * 64;
            const int srow = lane >> 3;          // 0..7
            const int scol = (lane & 7) * 4;     // u32 idx within row
#pragma unroll
            for (int r = 0; r < 8; r++) {
                const unsigned int* g = Ap_g
                    + ((size_t)(k0 >> 5) * rowsTot + m0 + half + r * 8 + srow) * 32 + scol;
                unsigned int* l = Ap_s + (half + r * 8) * 32;
                async16(g, l);
            }
        } else {
            const unsigned short* gmat = (wid == 2) ? Bthi_g : Btlo_g;
            short* lmat = (wid == 2) ? Bhi_s : Blo_s;
            const int srow = lane >> 2;
            const int skq  = (lane & 3) * 8;
#pragma unroll
            for (int r = 0; r < 8; r++) {
                const unsigned short* g = gmat + (size_t)(n0 + r * 16 + srow) * 256 + k0 + skq;
                short* l = lmat + (r * 16) * 32;
                async16(g, l);
            }
        }
        __syncthreads();

        short8 ah[4], al[4], bh[4], bl[4];
#pragma unroll
        for (int f = 0; f < 4; f++) {
            const uint4* ap = (const uint4*)&Ap_s[(wm + f * 16 + lrow) * 32 + lk];
            uint4 a0 = ap[0], a1 = ap[1];
            union { unsigned int u[4]; short8 s; } uh, ul;
            uh.u[0] = __builtin_amdgcn_perm(a0.y, a0.x, 0x07060302u);
            uh.u[1] = __builtin_amdgcn_perm(a0.w, a0.z, 0x07060302u);
            uh.u[2] = __builtin_amdgcn_perm(a1.y, a1.x, 0x07060302u);
            uh.u[3] = __builtin_amdgcn_perm(a1.w, a1.z, 0x07060302u);
            ul.u[0] = __builtin_amdgcn_perm(a0.y, a0.x, 0x05040100u);
            ul.u[1] = __builtin_amdgcn_perm(a0.w, a0.z, 0x05040100u);
            ul.u[2] = __builtin_amdgcn_perm(a1.y, a1.x, 0x05040100u);
            ul.u[3] = __builtin_amdgcn_perm(a1.w, a1.z, 0x05040100u);
            ah[f] = uh.s; al[f] = ul.s;
            bh[f] = *(const short8*)&Bhi_s[(wn + f * 16 + lrow) * 32 + lk];
            bl[f] = *(const short8*)&Blo_s[(wn + f * 16 + lrow) * 32 + lk];
        }
#pragma unroll
        for (int i = 0; i < 4; i++)
#pragma unroll
            for (int j = 0; j < 4; j++) {
                acc[i][j] = __builtin_amdgcn_mfma_f32_16x16x32_bf16(ah[i], bh[j], acc[i][j], 0, 0, 0);
                acc[i][j] = __builtin_amdgcn_mfma_f32_16x16x32_bf16(ah[i], bl[j], acc[i][j], 0, 0, 0);
                acc[i][j] = __builtin_amdgcn_mfma_f32_16x16x32_bf16(al[i], bh[j], acc[i][j], 0, 0, 0);
            }
        __syncthreads();
    }

    const int ccol0 = lane & 15;
    const int crow0 = (lane >> 4) * 4;
    float bvv[4];
#pragma unroll
    for (int j = 0; j < 4; j++)
        bvv[j] = bo[n0 + wn + j * 16 + ccol0];
#pragma unroll
    for (int i = 0; i < 4; i++) {
#pragma unroll
        for (int r = 0; r < 4; r++) {
            const int row = m0 + wm + i * 16 + crow0 + r;
#pragma unroll
            for (int j = 0; j < 4; j++) {
                const int col = n0 + wn + j * 16 + ccol0;
                C[(size_t)row * 256 + col] = acc[i][j][r] + bvv[j];
            }
        }
    }
}

// ---------------- MFMA attention: block=(s,h), 4 waves x 64 q-rows ----------------
// q,k,v,g,opack all HEAD-MAJOR [h][row][32] -> contiguous per-block I/O.
// S^T = K·Q^T; C-layout (4 consecutive kk/lane) feeds 16x16x16 PV directly AND
// matches one float4 bias load per fragment ([h][q][k] layout).
// softmax in exp2 domain (scale & bias pre-multiplied by log2 e).
__global__ void __launch_bounds__(256, 4)
attn_mfma_kernel(const unsigned short* __restrict__ q, const unsigned short* __restrict__ k,
                 const unsigned short* __restrict__ v, const float* __restrict__ bias_qk,
                 const unsigned short* __restrict__ g,
                 unsigned int* __restrict__ opack, int rows) {
    const int s = blockIdx.x, h = blockIdx.y;
    __shared__ short Ks[256][40];    // K bf16 [kk][c]            20480 B
    __shared__ short Vs[32][268];    // V^T bf16 [c][kk]          17152 B
    __shared__ float li_s[4][64];    //                             1024 B  => 38656 B
    const int tid = threadIdx.x;
    const int w = tid >> 6, l = tid & 63;
    const int lg = l >> 4, l15 = l & 15;
    const size_t hb = ((size_t)h * rows + (size_t)s * NRES) * 32;  // head-major base

    // ---- stage K (row-major) and V (transposed); fully coalesced contiguous reads ----
    {
        const int kk0 = tid >> 2;          // 0..63
        const int c8 = (tid & 3) * 8;      // 0,8,16,24
#pragma unroll
        for (int r4 = 0; r4 < 4; r4++) {
            const int kk = r4 * 64 + kk0;
            const size_t gi = hb + (size_t)kk * 32 + c8;
            short8 k8 = *(const short8*)(k + gi);
            short8 v8 = *(const short8*)(v + gi);
            *(short8*)&Ks[kk][c8] = k8;
#pragma unroll
            for (int jj = 0; jj < 8; jj++) Vs[c8 + jj][kk] = v8[jj];
        }
    }
    // ---- Q fragments straight from global bf16 (B-operand: col=l15, k=lg*8..+8) ----
    const int wq0 = w * 64;
    short8 qf[4];
#pragma unroll
    for (int mq = 0; mq < 4; mq++)
        qf[mq] = *(const short8*)(q + hb + (size_t)(wq0 + mq * 16 + l15) * 32 + lg * 8);
    __syncthreads();

    f32x4 acco[4][2];
#pragma unroll
    for (int mq = 0; mq < 4; mq++)
#pragma unroll
        for (int nc = 0; nc < 2; nc++) acco[mq][nc] = (f32x4){0.f, 0.f, 0.f, 0.f};
    float lip[4] = {0.f, 0.f, 0.f, 0.f};
    const float* bh = bias_qk + (size_t)h * NROW;

    for (int ch = 0; ch < 8; ch++) {
        const int kb = ch * 32;
        short8 kf[2];
#pragma unroll
        for (int ik = 0; ik < 2; ik++)
            kf[ik] = *(const short8*)&Ks[kb + ik * 16 + l15][lg * 8];
#pragma unroll
        for (int ik = 0; ik < 2; ik++) {
            // V fragments (B-frag of 16x16x16: col=l15, k=lg*4..+3)
            s16x4 vf[2];
#pragma unroll
            for (int nc = 0; nc < 2; nc++)
                vf[nc] = *(const s16x4*)&Vs[nc * 16 + l15][kb + ik * 16 + lg * 4];
            const int kkr = ik * 16 + lg * 4;   // chunk-local kk of reg 0
#pragma unroll
            for (int jq = 0; jq < 4; jq++) {
                const int qrow = wq0 + jq * 16 + l15;
                f32x4 sa = (f32x4){0.f, 0.f, 0.f, 0.f};
                sa = __builtin_amdgcn_mfma_f32_16x16x32_bf16(kf[ik], qf[jq], sa, 0, 0, 0);
                // one float4 bias load: [h][q][k], kk consecutive == C-layout regs
                float4 bv = *(const float4*)(bh + (size_t)qrow * NRES + kb + kkr);
                const float p0 = __builtin_amdgcn_exp2f(sa[0] + bv.x);
                const float p1 = __builtin_amdgcn_exp2f(sa[1] + bv.y);
                const float p2 = __builtin_amdgcn_exp2f(sa[2] + bv.z);
                const float p3 = __builtin_amdgcn_exp2f(sa[3] + bv.w);
                lip[jq] += (p0 + p1) + (p2 + p3);
                s16x4 pa;
                pa[0] = (short)f2bf(p0); pa[1] = (short)f2bf(p1);
                pa[2] = (short)f2bf(p2); pa[3] = (short)f2bf(p3);
                // P (C-layout of S^T) IS the 16x16x16 A-frag: row=l15, k=lg*4+j
#pragma unroll
                for (int nc = 0; nc < 2; nc++)
                    acco[jq][nc] = __builtin_amdgcn_mfma_f32_16x16x16bf16_1k(
                        pa, vf[nc], acco[jq][nc], 0, 0, 0);
            }
        }
    }

    // ---- row-sum reduction across lane groups; remap via tiny LDS ----
#pragma unroll
    for (int jq = 0; jq < 4; jq++) {
        lip[jq] += __shfl_xor(lip[jq], 16);
        lip[jq] += __shfl_xor(lip[jq], 32);
        li_s[w][jq * 16 + l15] = lip[jq];
    }

    // ---- epilogue: O/li * g, bf16 hi/lo packed u32, head-major full-line stores ----
#pragma unroll
    for (int mq = 0; mq < 4; mq++) {
#pragma unroll
        for (int r = 0; r < 4; r++) {
            const int qrow = wq0 + mq * 16 + lg * 4 + r;
            const float inv = 1.0f / li_s[w][mq * 16 + lg * 4 + r];
            const size_t rb = hb + (size_t)qrow * 32;
#pragma unroll
            for (int nc = 0; nc < 2; nc++) {
                const int c = nc * 16 + l15;
                const float val = acco[mq][nc][r] * inv * bf2f(g[rb + c]);
                const unsigned short hi = f2bf(val);
                const unsigned short lo = f2bf(val - bf2f(hi));
                opack[rb + c] = ((unsigned int)hi << 16) | lo;
            }
        }
    }
}

extern "C" void kernel_launch(void* const* d_in, const int* in_sizes, int n_in,
                              void* d_out, int out_size, void* d_ws, size_t ws_size,
                              hipStream_t stream) {
    const float* m    = (const float*)d_in[0];
    const float* z    = (const float*)d_in[1];
    const float* lnmw = (const float*)d_in[2];
    const float* lnmb = (const float*)d_in[3];
    const float* lnzw = (const float*)d_in[4];
    const float* lnzb = (const float*)d_in[5];
    const float* Wz   = (const float*)d_in[6];
    const float* Wq   = (const float*)d_in[7];
    const float* Wk   = (const float*)d_in[8];
    const float* Wv   = (const float*)d_in[9];
    const float* Wg   = (const float*)d_in[10];
    const float* bg   = (const float*)d_in[11];
    const float* Wo   = (const float*)d_in[12];
    const float* bo   = (const float*)d_in[13];
    float* out = (float*)d_out;

    char* wsb = (char*)d_ws;
    const size_t BIASB = (size_t)NHEAD * NROW * 4;   // 2 MB
    const size_t WBFB  = (size_t)6 * 65536 * 2;      // 768 KB
    float* bias_qk = (float*)wsb;
    unsigned short* wbf = (unsigned short*)(wsb + BIASB);
    char* chunk0 = wsb + BIASB + ((WBFB + 255) & ~(size_t)255);

    // Per-s-elem: q,k,v,g,mbf bf16 (10 B) + opack u32 (4 B) = 14 B
    const size_t avail = ws_size - (size_t)(chunk0 - wsb);
    int SC = NSEQ;
    while (SC > 1 && (size_t)SC * NRES * CM * 14 > avail) SC >>= 1;
    const size_t CHE = (size_t)SC * NRES * CM;

    unsigned short* qb  = (unsigned short*)chunk0;
    unsigned short* kb  = qb + CHE;
    unsigned short* vb  = kb + CHE;
    unsigned short* gb  = vb + CHE;
    unsigned short* mbf = gb + CHE;
    unsigned int* opk   = (unsigned int*)(mbf + CHE);

    ln_z_bias_kernel<<<NROW, 64, 0, stream>>>(z, lnzw, lnzb, Wz, bias_qk);
    wsplit_kernel<<<dim3(256, 5), 256, 0, stream>>>(Wq, Wk, Wv, Wg, Wo, wbf);

    const int rows = SC * NRES;
    const int mtiles = rows / 128;
    // scale * log2(e): softmax runs in exp2 domain
    const float scale = 0.17677669529663687f * 1.4426950408889634f;

    for (int s0 = 0; s0 < NSEQ; s0 += SC) {
        const float* m_c   = m   + (size_t)s0 * NRES * CM;
        float*       out_c = out + (size_t)s0 * NRES * CM;

        ln_m_kernel<<<rows, 64, 0, stream>>>(m_c, lnmw, lnmb, mbf);

        gemm_qkvg_kernel<<<dim3(8, mtiles), 256, 0, stream>>>(
            mbf, wbf, qb, kb, vb, gb, bg, scale, rows);

        attn_mfma_kernel<<<dim3(SC, NHEAD), 256, 0, stream>>>(
            qb, kb, vb, bias_qk, gb, opk, rows);

        gemm_out_kernel<<<dim3(2, mtiles), 256, 0, stream>>>(
            opk, wbf, out_c, bo, rows);
    }
}

// Round 5
// 370.006 us; speedup vs baseline: 1.0788x; 1.0084x over previous
//
#include <hip/hip_runtime.h>
#include <cmath>

#define NSEQ 256
#define NRES 256
#define CM   256
#define CZ   128
#define NHEAD 8
#define CHD  32
#define NROW 65536   // NSEQ*NRES == NRES*NRES (total m rows)

typedef __attribute__((ext_vector_type(8))) short short8;
typedef __attribute__((ext_vector_type(4))) short s16x4;
typedef __attribute__((ext_vector_type(4))) float f32x4;

// ---- raw bf16 conversion ----
__device__ __forceinline__ unsigned short f2bf(float x) {   // round-nearest-even
    union { float f; unsigned int u; } v; v.f = x;
    unsigned int u = v.u;
    u += 0x7fffu + ((u >> 16) & 1u);
    return (unsigned short)(u >> 16);
}
__device__ __forceinline__ float bf2f(unsigned short b) {
    union { float f; unsigned int u; } v; v.u = ((unsigned int)b) << 16;
    return v.f;
}

// async global->LDS, 16B per lane; LDS dest = uniform base + lane*16
__device__ __forceinline__ void async16(const void* g, void* l) {
    __builtin_amdgcn_global_load_lds(
        (const __attribute__((address_space(1))) unsigned int*)g,
        (__attribute__((address_space(3))) unsigned int*)l, 16, 0, 0);
}

// XCD-aware remap: linear block id b -> XCD b%8. Group the nx column-slabs
// sharing one A m-panel consecutively on the SAME XCD. Bijective when ny%8==0.
__device__ __forceinline__ void xcd_remap(int& x, int& y) {
    const int nx = gridDim.x, ny = gridDim.y;
    const int b = blockIdx.x + blockIdx.y * nx;
    if ((ny & 7) == 0) {
        const int c = b & 7;
        const int t = b >> 3;
        x = t % nx;
        y = c + 8 * (t / nx);
    } else {
        x = blockIdx.x; y = blockIdx.y;
    }
}

// ---------------- LayerNorm over m rows -> single bf16 ----------------
__global__ void __launch_bounds__(64)
ln_m_kernel(const float* __restrict__ m, const float* __restrict__ w,
            const float* __restrict__ b, unsigned short* __restrict__ mbf) {
    const int row = blockIdx.x;
    const int t = threadIdx.x;  // 0..63, one float4 each
    const float* x = m + (size_t)row * CM;
    float4 xv = *(const float4*)(x + t * 4);
    float s  = xv.x + xv.y + xv.z + xv.w;
    float s2 = xv.x * xv.x + xv.y * xv.y + xv.z * xv.z + xv.w * xv.w;
#pragma unroll
    for (int off = 32; off > 0; off >>= 1) {
        s  += __shfl_xor(s, off);
        s2 += __shfl_xor(s2, off);
    }
    const float mu  = s * (1.0f / CM);
    const float var = s2 * (1.0f / CM) - mu * mu;
    const float inv = rsqrtf(var + 1e-5f);
    float4 wv = *(const float4*)(w + t * 4);
    float4 bv = *(const float4*)(b + t * 4);
    ushort4 o4;
    o4.x = f2bf((xv.x - mu) * inv * wv.x + bv.x);
    o4.y = f2bf((xv.y - mu) * inv * wv.y + bv.y);
    o4.z = f2bf((xv.z - mu) * inv * wv.z + bv.z);
    o4.w = f2bf((xv.w - mu) * inv * wv.w + bv.w);
    *(ushort4*)(mbf + (size_t)row * CM + t * 4) = o4;
}

// ---------------- LayerNorm over z rows + pair bias; bias pre-scaled by log2(e) ----------------
__global__ void __launch_bounds__(64)
ln_z_bias_kernel(const float* __restrict__ z, const float* __restrict__ w,
                 const float* __restrict__ b, const float* __restrict__ Wz,
                 float* __restrict__ bias) {
    const int pair = blockIdx.x;  // q*256 + k
    const int t = threadIdx.x;    // 0..63, two floats each
    const float* x = z + (size_t)pair * CZ;
    float2 xv = *(const float2*)(x + t * 2);
    float s  = xv.x + xv.y;
    float s2 = xv.x * xv.x + xv.y * xv.y;
#pragma unroll
    for (int off = 32; off > 0; off >>= 1) {
        s  += __shfl_xor(s, off);
        s2 += __shfl_xor(s2, off);
    }
    const float mu  = s * (1.0f / CZ);
    const float var = s2 * (1.0f / CZ) - mu * mu;
    const float inv = rsqrtf(var + 1e-5f);
    float2 wv = *(const float2*)(w + t * 2);
    float2 bv = *(const float2*)(b + t * 2);
    const float zn0 = (xv.x - mu) * inv * wv.x + bv.x;
    const float zn1 = (xv.y - mu) * inv * wv.y + bv.y;
    float ph[NHEAD];
#pragma unroll
    for (int h = 0; h < NHEAD; h++)
        ph[h] = zn0 * Wz[(2 * t) * NHEAD + h] + zn1 * Wz[(2 * t + 1) * NHEAD + h];
#pragma unroll
    for (int h = 0; h < NHEAD; h++) {
#pragma unroll
        for (int off = 32; off > 0; off >>= 1) ph[h] += __shfl_xor(ph[h], off);
    }
    if (t == 0) {
#pragma unroll
        for (int h = 0; h < NHEAD; h++)
            bias[(size_t)h * NROW + pair] = ph[h] * 1.4426950408889634f;  // log2(e) folded
    }
}

// ---------------- weight transpose: Wq/Wk/Wv/Wg -> single bf16, Wo -> hi/lo ----------------
__global__ void __launch_bounds__(256)
wsplit_kernel(const float* __restrict__ Wq, const float* __restrict__ Wk,
              const float* __restrict__ Wv, const float* __restrict__ Wg,
              const float* __restrict__ Wo, unsigned short* __restrict__ wbf) {
    const int n = blockIdx.x;        // output row (col of W)
    const int mat = blockIdx.y;      // 0..4
    const int k = threadIdx.x;       // 0..255
    const float* W = (mat == 0) ? Wq : (mat == 1) ? Wk : (mat == 2) ? Wv
                   : (mat == 3) ? Wg : Wo;
    const float v = W[(size_t)k * 256 + n];
    unsigned short h = f2bf(v);
    unsigned short* hi = wbf + (size_t)mat * 65536;
    hi[(size_t)n * 256 + k] = h;
    if (mat == 4) {
        unsigned short* lo = wbf + (size_t)5 * 65536;
        lo[(size_t)n * 256 + k] = f2bf(v - bf2f(h));
    }
}

// fused Q/K/V/G projection: BK=64, XOR-swizzled LDS (bank-conflict-free),
// LDS-staged vectorized head-major epilogue.
__global__ void __launch_bounds__(256)
gemm_qkvg_kernel(const unsigned short* __restrict__ A,
                 const unsigned short* __restrict__ wbf,
                 unsigned short* __restrict__ qb, unsigned short* __restrict__ kb,
                 unsigned short* __restrict__ vb, unsigned short* __restrict__ gb,
                 const float* __restrict__ bg, float scale, int rowsTot) {
    __shared__ short LDS[128 * 128];          // 32 KB: A=[0,8K), B=[8K,16K) shorts
    short* A_s = LDS;
    short* B_s = LDS + 128 * 64;
    int bx, by;
    xcd_remap(bx, by);
    const int which = bx >> 1;
    const int n0 = (bx & 1) * 128;
    const int m0 = by * 128;
    const unsigned short* Bt_g = wbf + (size_t)which * 65536;
    unsigned short* C = (which == 0) ? qb : (which == 1) ? kb : (which == 2) ? vb : gb;
    const float alpha = (which == 0) ? scale : 1.0f;
    const float* bias = (which == 3) ? bg : nullptr;
    const int act = (which == 3) ? 1 : 0;

    const int tid  = threadIdx.x;
    const int wid  = tid >> 6;
    const int lane = tid & 63;
    const int wm = (wid >> 1) * 64;
    const int wn = (wid & 1) * 64;

    f32x4 acc[4][4];
#pragma unroll
    for (int i = 0; i < 4; i++)
#pragma unroll
        for (int j = 0; j < 4; j++) acc[i][j] = (f32x4){0.f, 0.f, 0.f, 0.f};

    // staging: waves 0,1 -> A halves; waves 2,3 -> B halves. Row = 128 B (8 slots
    // of 16 B). Physical slot = logical ^ (row&7); dest linear, SOURCE pre-swizzled.
    const unsigned short* gmat = (wid < 2) ? A : Bt_g;
    short* lmat = (wid < 2) ? A_s : B_s;
    const int brow = (wid < 2) ? m0 : n0;
    const int half = (wid & 1) * 64;
    const int srow  = lane >> 3;                  // 0..7 row within 8-row group
    const int sslot = (lane & 7) ^ srow;          // pre-swizzled logical slot

    const int lrow = lane & 15;
    const int lg   = lane >> 4;
    // read-side physical slots (elem offsets) for the two 32-k chunks
    const int x0 = ((0 + lg) ^ (lane & 7)) * 8;
    const int x1 = ((4 + lg) ^ (lane & 7)) * 8;

    for (int k0 = 0; k0 < 256; k0 += 64) {
#pragma unroll
        for (int r = 0; r < 8; r++) {
            const unsigned short* g = gmat
                + (size_t)(brow + half + r * 8 + srow) * 256 + k0 + sslot * 8;
            short* l = lmat + (half + r * 8) * 64;   // HW adds lane*16B
            async16(g, l);
        }
        __syncthreads();   // drains vmcnt -> tiles complete

#pragma unroll
        for (int kk = 0; kk < 2; kk++) {
            const int x = kk ? x1 : x0;
            short8 af[4], bf[4];
#pragma unroll
            for (int f = 0; f < 4; f++) {
                af[f] = *(const short8*)&A_s[(wm + f * 16 + lrow) * 64 + x];
                bf[f] = *(const short8*)&B_s[(wn + f * 16 + lrow) * 64 + x];
            }
#pragma unroll
            for (int i = 0; i < 4; i++)
#pragma unroll
                for (int j = 0; j < 4; j++)
                    acc[i][j] = __builtin_amdgcn_mfma_f32_16x16x32_bf16(af[i], bf[j], acc[i][j], 0, 0, 0);
        }
        __syncthreads();   // safe to re-stage
    }

    // ---- epilogue: acc -> LDS (bf16 C tile), then vectorized head-major stores ----
    {
        const int ccol0 = lane & 15;
        const int crow0 = lg * 4;
        float bvv[4];
#pragma unroll
        for (int j = 0; j < 4; j++)
            bvv[j] = bias ? bias[n0 + wn + j * 16 + ccol0] : 0.0f;
#pragma unroll
        for (int i = 0; i < 4; i++)
#pragma unroll
            for (int r = 0; r < 4; r++) {
                const int row = wm + i * 16 + crow0 + r;
#pragma unroll
                for (int j = 0; j < 4; j++) {
                    float vv = acc[i][j][r] * alpha + bvv[j];
                    if (act == 1) vv = 1.0f / (1.0f + __expf(-vv));
                    LDS[row * 128 + wn + j * 16 + ccol0] = (short)f2bf(vv);
                }
            }
        __syncthreads();
        // stream out: tile row-major -> head-major planes, 16B/lane fully coalesced
        const int rr = tid >> 4;            // row within 16-row group
        const int cb = (tid & 15) * 8;      // col elem base
        const int pl = n0 / 32 + (cb >> 5); // head plane
        const int cw = cb & 31;
#pragma unroll
        for (int t = 0; t < 8; t++) {
            const int row = t * 16 + rr;
            short8 vv = *(const short8*)&LDS[row * 128 + cb];
            *(short8*)&C[((size_t)pl * rowsTot + m0 + row) * 32 + cw] = vv;
        }
    }
}

// output projection: C = (g*o) @ Wo + bo. A = packed u32 (hi<<16|lo) HEAD-MAJOR.
__global__ void __launch_bounds__(256)
gemm_out_kernel(const unsigned int* __restrict__ Ap_g,
                const unsigned short* __restrict__ wbf, float* __restrict__ C,
                const float* __restrict__ bo, int rowsTot) {
    __shared__ unsigned int Ap_s[128 * 32];  // 16 KB
    __shared__ short Bhi_s[128 * 32];        // 8 KB
    __shared__ short Blo_s[128 * 32];        // 8 KB
    int bx, by;
    xcd_remap(bx, by);
    const int m0 = by * 128, n0 = bx * 128;
    const unsigned short* Bthi_g = wbf + (size_t)4 * 65536;
    const unsigned short* Btlo_g = wbf + (size_t)5 * 65536;

    const int tid  = threadIdx.x;
    const int wid  = tid >> 6;
    const int lane = tid & 63;
    const int wm = (wid >> 1) * 64;
    const int wn = (wid & 1) * 64;

    f32x4 acc[4][4];
#pragma unroll
    for (int i = 0; i < 4; i++)
#pragma unroll
        for (int j = 0; j < 4; j++) acc[i][j] = (f32x4){0.f, 0.f, 0.f, 0.f};

    const int lrow = lane & 15;
    const int lk   = (lane >> 4) * 8;

    for (int k0 = 0; k0 < 256; k0 += 32) {
        if (wid < 2) {
            // A head-major: k0 block == head plane (k0>>5); rows of 32 u32 = 128B
            const int half = wid * 64;
            const int srow = lane >> 3;          // 0..7
            const int scol = (lane & 7) * 4;     // u32 idx within row
#pragma unroll
            for (int r = 0; r < 8; r++) {
                const unsigned int* g = Ap_g
                    + ((size_t)(k0 >> 5) * rowsTot + m0 + half + r * 8 + srow) * 32 + scol;
                unsigned int* l = Ap_s + (half + r * 8) * 32;
                async16(g, l);
            }
        } else {
            const unsigned short* gmat = (wid == 2) ? Bthi_g : Btlo_g;
            short* lmat = (wid == 2) ? Bhi_s : Blo_s;
            const int srow = lane >> 2;
            const int skq  = (lane & 3) * 8;
#pragma unroll
            for (int r = 0; r < 8; r++) {
                const unsigned short* g = gmat + (size_t)(n0 + r * 16 + srow) * 256 + k0 + skq;
                short* l = lmat + (r * 16) * 32;
                async16(g, l);
            }
        }
        __syncthreads();

        short8 ah[4], al[4], bh[4], bl[4];
#pragma unroll
        for (int f = 0; f < 4; f++) {
            const uint4* ap = (const uint4*)&Ap_s[(wm + f * 16 + lrow) * 32 + lk];
            uint4 a0 = ap[0], a1 = ap[1];
            union { unsigned int u[4]; short8 s; } uh, ul;
            uh.u[0] = __builtin_amdgcn_perm(a0.y, a0.x, 0x07060302u);
            uh.u[1] = __builtin_amdgcn_perm(a0.w, a0.z, 0x07060302u);
            uh.u[2] = __builtin_amdgcn_perm(a1.y, a1.x, 0x07060302u);
            uh.u[3] = __builtin_amdgcn_perm(a1.w, a1.z, 0x07060302u);
            ul.u[0] = __builtin_amdgcn_perm(a0.y, a0.x, 0x05040100u);
            ul.u[1] = __builtin_amdgcn_perm(a0.w, a0.z, 0x05040100u);
            ul.u[2] = __builtin_amdgcn_perm(a1.y, a1.x, 0x05040100u);
            ul.u[3] = __builtin_amdgcn_perm(a1.w, a1.z, 0x05040100u);
            ah[f] = uh.s; al[f] = ul.s;
            bh[f] = *(const short8*)&Bhi_s[(wn + f * 16 + lrow) * 32 + lk];
            bl[f] = *(const short8*)&Blo_s[(wn + f * 16 + lrow) * 32 + lk];
        }
#pragma unroll
        for (int i = 0; i < 4; i++)
#pragma unroll
            for (int j = 0; j < 4; j++) {
                acc[i][j] = __builtin_amdgcn_mfma_f32_16x16x32_bf16(ah[i], bh[j], acc[i][j], 0, 0, 0);
                acc[i][j] = __builtin_amdgcn_mfma_f32_16x16x32_bf16(ah[i], bl[j], acc[i][j], 0, 0, 0);
                acc[i][j] = __builtin_amdgcn_mfma_f32_16x16x32_bf16(al[i], bh[j], acc[i][j], 0, 0, 0);
            }
        __syncthreads();
    }

    const int ccol0 = lane & 15;
    const int crow0 = (lane >> 4) * 4;
    float bvv[4];
#pragma unroll
    for (int j = 0; j < 4; j++)
        bvv[j] = bo[n0 + wn + j * 16 + ccol0];
#pragma unroll
    for (int i = 0; i < 4; i++) {
#pragma unroll
        for (int r = 0; r < 4; r++) {
            const int row = m0 + wm + i * 16 + crow0 + r;
#pragma unroll
            for (int j = 0; j < 4; j++) {
                const int col = n0 + wn + j * 16 + ccol0;
                C[(size_t)row * 256 + col] = acc[i][j][r] + bvv[j];
            }
        }
    }
}

// ---------------- MFMA attention: block=(s,h), 4 waves x 64 q-rows ----------------
// q,k,v,g,opack all HEAD-MAJOR [h][row][32] -> contiguous per-block I/O.
// S^T = K·Q^T; C-layout (4 consecutive kk/lane) feeds 16x16x16 PV directly AND
// matches one float4 bias load per fragment ([h][q][k] layout).
// softmax in exp2 domain (scale & bias pre-multiplied by log2 e).
__global__ void __launch_bounds__(256, 4)
attn_mfma_kernel(const unsigned short* __restrict__ q, const unsigned short* __restrict__ k,
                 const unsigned short* __restrict__ v, const float* __restrict__ bias_qk,
                 const unsigned short* __restrict__ g,
                 unsigned int* __restrict__ opack, int rows) {
    const int s = blockIdx.x, h = blockIdx.y;
    __shared__ short Ks[256][40];    // K bf16 [kk][c]            20480 B
    __shared__ short Vs[32][268];    // V^T bf16 [c][kk]          17152 B
    __shared__ float li_s[4][64];    //                             1024 B  => 38656 B
    const int tid = threadIdx.x;
    const int w = tid >> 6, l = tid & 63;
    const int lg = l >> 4, l15 = l & 15;
    const size_t hb = ((size_t)h * rows + (size_t)s * NRES) * 32;  // head-major base

    // ---- stage K (row-major) and V (transposed); fully coalesced contiguous reads ----
    {
        const int kk0 = tid >> 2;          // 0..63
        const int c8 = (tid & 3) * 8;      // 0,8,16,24
#pragma unroll
        for (int r4 = 0; r4 < 4; r4++) {
            const int kk = r4 * 64 + kk0;
            const size_t gi = hb + (size_t)kk * 32 + c8;
            short8 k8 = *(const short8*)(k + gi);
            short8 v8 = *(const short8*)(v + gi);
            *(short8*)&Ks[kk][c8] = k8;
#pragma unroll
            for (int jj = 0; jj < 8; jj++) Vs[c8 + jj][kk] = v8[jj];
        }
    }
    // ---- Q fragments straight from global bf16 (B-operand: col=l15, k=lg*8..+8) ----
    const int wq0 = w * 64;
    short8 qf[4];
#pragma unroll
    for (int mq = 0; mq < 4; mq++)
        qf[mq] = *(const short8*)(q + hb + (size_t)(wq0 + mq * 16 + l15) * 32 + lg * 8);
    __syncthreads();

    f32x4 acco[4][2];
#pragma unroll
    for (int mq = 0; mq < 4; mq++)
#pragma unroll
        for (int nc = 0; nc < 2; nc++) acco[mq][nc] = (f32x4){0.f, 0.f, 0.f, 0.f};
    float lip[4] = {0.f, 0.f, 0.f, 0.f};
    const float* bh = bias_qk + (size_t)h * NROW;

    for (int ch = 0; ch < 8; ch++) {
        const int kb = ch * 32;
        short8 kf[2];
#pragma unroll
        for (int ik = 0; ik < 2; ik++)
            kf[ik] = *(const short8*)&Ks[kb + ik * 16 + l15][lg * 8];
#pragma unroll
        for (int ik = 0; ik < 2; ik++) {
            // V fragments (B-frag of 16x16x16: col=l15, k=lg*4..+3)
            s16x4 vf[2];
#pragma unroll
            for (int nc = 0; nc < 2; nc++)
                vf[nc] = *(const s16x4*)&Vs[nc * 16 + l15][kb + ik * 16 + lg * 4];
            const int kkr = ik * 16 + lg * 4;   // chunk-local kk of reg 0
#pragma unroll
            for (int jq = 0; jq < 4; jq++) {
                const int qrow = wq0 + jq * 16 + l15;
                f32x4 sa = (f32x4){0.f, 0.f, 0.f, 0.f};
                sa = __builtin_amdgcn_mfma_f32_16x16x32_bf16(kf[ik], qf[jq], sa, 0, 0, 0);
                // one float4 bias load: [h][q][k], kk consecutive == C-layout regs
                float4 bv = *(const float4*)(bh + (size_t)qrow * NRES + kb + kkr);
                const float p0 = __builtin_amdgcn_exp2f(sa[0] + bv.x);
                const float p1 = __builtin_amdgcn_exp2f(sa[1] + bv.y);
                const float p2 = __builtin_amdgcn_exp2f(sa[2] + bv.z);
                const float p3 = __builtin_amdgcn_exp2f(sa[3] + bv.w);
                lip[jq] += (p0 + p1) + (p2 + p3);
                s16x4 pa;
                pa[0] = (short)f2bf(p0); pa[1] = (short)f2bf(p1);
                pa[2] = (short)f2bf(p2); pa[3] = (short)f2bf(p3);
                // P (C-layout of S^T) IS the 16x16x16 A-frag: row=l15, k=lg*4+j
#pragma unroll
                for (int nc = 0; nc < 2; nc++)
                    acco[jq][nc] = __builtin_amdgcn_mfma_f32_16x16x16bf16_1k(
                        pa, vf[nc], acco[jq][nc], 0, 0, 0);
            }
        }
    }

    // ---- row-sum reduction across lane groups; remap via tiny LDS ----
#pragma unroll
    for (int jq = 0; jq < 4; jq++) {
        lip[jq] += __shfl_xor(lip[jq], 16);
        lip[jq] += __shfl_xor(lip[jq], 32);
        li_s[w][jq * 16 + l15] = lip[jq];
    }

    // ---- epilogue: O/li * g, bf16 hi/lo packed u32, head-major full-line stores ----
#pragma unroll
    for (int mq = 0; mq < 4; mq++) {
#pragma unroll
        for (int r = 0; r < 4; r++) {
            const int qrow = wq0 + mq * 16 + lg * 4 + r;
            const float inv = 1.0f / li_s[w][mq * 16 + lg * 4 + r];
            const size_t rb = hb + (size_t)qrow * 32;
#pragma unroll
            for (int nc = 0; nc < 2; nc++) {
                const int c = nc * 16 + l15;
                const float val = acco[mq][nc][r] * inv * bf2f(g[rb + c]);
                const unsigned short hi = f2bf(val);
                const unsigned short lo = f2bf(val - bf2f(hi));
                opack[rb + c] = ((unsigned int)hi << 16) | lo;
            }
        }
    }
}

extern "C" void kernel_launch(void* const* d_in, const int* in_sizes, int n_in,
                              void* d_out, int out_size, void* d_ws, size_t ws_size,
                              hipStream_t stream) {
    const float* m    = (const float*)d_in[0];
    const float* z    = (const float*)d_in[1];
    const float* lnmw = (const float*)d_in[2];
    const float* lnmb = (const float*)d_in[3];
    const float* lnzw = (const float*)d_in[4];
    const float* lnzb = (const float*)d_in[5];
    const float* Wz   = (const float*)d_in[6];
    const float* Wq   = (const float*)d_in[7];
    const float* Wk   = (const float*)d_in[8];
    const float* Wv   = (const float*)d_in[9];
    const float* Wg   = (const float*)d_in[10];
    const float* bg   = (const float*)d_in[11];
    const float* Wo   = (const float*)d_in[12];
    const float* bo   = (const float*)d_in[13];
    float* out = (float*)d_out;

    char* wsb = (char*)d_ws;
    const size_t BIASB = (size_t)NHEAD * NROW * 4;   // 2 MB
    const size_t WBFB  = (size_t)6 * 65536 * 2;      // 768 KB
    float* bias_qk = (float*)wsb;
    unsigned short* wbf = (unsigned short*)(wsb + BIASB);
    char* chunk0 = wsb + BIASB + ((WBFB + 255) & ~(size_t)255);

    // Per-s-elem: q,k,v,g,mbf bf16 (10 B) + opack u32 (4 B) = 14 B
    const size_t avail = ws_size - (size_t)(chunk0 - wsb);
    int SC = NSEQ;
    while (SC > 1 && (size_t)SC * NRES * CM * 14 > avail) SC >>= 1;
    const size_t CHE = (size_t)SC * NRES * CM;

    unsigned short* qb  = (unsigned short*)chunk0;
    unsigned short* kb  = qb + CHE;
    unsigned short* vb  = kb + CHE;
    unsigned short* gb  = vb + CHE;
    unsigned short* mbf = gb + CHE;
    unsigned int* opk   = (unsigned int*)(mbf + CHE);

    ln_z_bias_kernel<<<NROW, 64, 0, stream>>>(z, lnzw, lnzb, Wz, bias_qk);
    wsplit_kernel<<<dim3(256, 5), 256, 0, stream>>>(Wq, Wk, Wv, Wg, Wo, wbf);

    const int rows = SC * NRES;
    const int mtiles = rows / 128;
    // scale * log2(e): softmax runs in exp2 domain
    const float scale = 0.17677669529663687f * 1.4426950408889634f;

    for (int s0 = 0; s0 < NSEQ; s0 += SC) {
        const float* m_c   = m   + (size_t)s0 * NRES * CM;
        float*       out_c = out + (size_t)s0 * NRES * CM;

        ln_m_kernel<<<rows, 64, 0, stream>>>(m_c, lnmw, lnmb, mbf);

        gemm_qkvg_kernel<<<dim3(8, mtiles), 256, 0, stream>>>(
            mbf, wbf, qb, kb, vb, gb, bg, scale, rows);

        attn_mfma_kernel<<<dim3(SC, NHEAD), 256, 0, stream>>>(
            qb, kb, vb, bias_qk, gb, opk, rows);

        gemm_out_kernel<<<dim3(2, mtiles), 256, 0, stream>>>(
            opk, wbf, out_c, bo, rows);
    }
}

// Round 7
// 347.613 us; speedup vs baseline: 1.1483x; 1.0644x over previous
//
#include <hip/hip_runtime.h>
#include <cmath>

#define NSEQ 256
#define NRES 256
#define CM   256
#define CZ   128
#define NHEAD 8
#define CHD  32
#define NROW 65536   // NSEQ*NRES == NRES*NRES (total m rows)

typedef __attribute__((ext_vector_type(8))) short short8;
typedef __attribute__((ext_vector_type(4))) short s16x4;
typedef __attribute__((ext_vector_type(4))) float f32x4;

// ---- raw bf16 conversion ----
__device__ __forceinline__ unsigned short f2bf(float x) {   // round-nearest-even
    union { float f; unsigned int u; } v; v.f = x;
    unsigned int u = v.u;
    u += 0x7fffu + ((u >> 16) & 1u);
    return (unsigned short)(u >> 16);
}
__device__ __forceinline__ float bf2f(unsigned short b) {
    union { float f; unsigned int u; } v; v.u = ((unsigned int)b) << 16;
    return v.f;
}

// async global->LDS, 16B per lane; LDS dest = uniform base + lane*16
__device__ __forceinline__ void async16(const void* g, void* l) {
    __builtin_amdgcn_global_load_lds(
        (const __attribute__((address_space(1))) unsigned int*)g,
        (__attribute__((address_space(3))) unsigned int*)l, 16, 0, 0);
}

// XCD-aware remap: linear block id b -> XCD b%8. Group the nx column-slabs
// sharing one A m-panel consecutively on the SAME XCD. Bijective when ny%8==0.
__device__ __forceinline__ void xcd_remap(int& x, int& y) {
    const int nx = gridDim.x, ny = gridDim.y;
    const int b = blockIdx.x + blockIdx.y * nx;
    if ((ny & 7) == 0) {
        const int c = b & 7;
        const int t = b >> 3;
        x = t % nx;
        y = c + 8 * (t / nx);
    } else {
        x = blockIdx.x; y = blockIdx.y;
    }
}

// ---------------- LayerNorm over m rows -> single bf16 ----------------
__global__ void __launch_bounds__(64)
ln_m_kernel(const float* __restrict__ m, const float* __restrict__ w,
            const float* __restrict__ b, unsigned short* __restrict__ mbf) {
    const int row = blockIdx.x;
    const int t = threadIdx.x;  // 0..63, one float4 each
    const float* x = m + (size_t)row * CM;
    float4 xv = *(const float4*)(x + t * 4);
    float s  = xv.x + xv.y + xv.z + xv.w;
    float s2 = xv.x * xv.x + xv.y * xv.y + xv.z * xv.z + xv.w * xv.w;
#pragma unroll
    for (int off = 32; off > 0; off >>= 1) {
        s  += __shfl_xor(s, off);
        s2 += __shfl_xor(s2, off);
    }
    const float mu  = s * (1.0f / CM);
    const float var = s2 * (1.0f / CM) - mu * mu;
    const float inv = rsqrtf(var + 1e-5f);
    float4 wv = *(const float4*)(w + t * 4);
    float4 bv = *(const float4*)(b + t * 4);
    ushort4 o4;
    o4.x = f2bf((xv.x - mu) * inv * wv.x + bv.x);
    o4.y = f2bf((xv.y - mu) * inv * wv.y + bv.y);
    o4.z = f2bf((xv.z - mu) * inv * wv.z + bv.z);
    o4.w = f2bf((xv.w - mu) * inv * wv.w + bv.w);
    *(ushort4*)(mbf + (size_t)row * CM + t * 4) = o4;
}

// ---------------- LayerNorm over z rows + pair bias; bias pre-scaled by log2(e) ----------------
__global__ void __launch_bounds__(64)
ln_z_bias_kernel(const float* __restrict__ z, const float* __restrict__ w,
                 const float* __restrict__ b, const float* __restrict__ Wz,
                 float* __restrict__ bias) {
    const int pair = blockIdx.x;  // q*256 + k
    const int t = threadIdx.x;    // 0..63, two floats each
    const float* x = z + (size_t)pair * CZ;
    float2 xv = *(const float2*)(x + t * 2);
    float s  = xv.x + xv.y;
    float s2 = xv.x * xv.x + xv.y * xv.y;
#pragma unroll
    for (int off = 32; off > 0; off >>= 1) {
        s  += __shfl_xor(s, off);
        s2 += __shfl_xor(s2, off);
    }
    const float mu  = s * (1.0f / CZ);
    const float var = s2 * (1.0f / CZ) - mu * mu;
    const float inv = rsqrtf(var + 1e-5f);
    float2 wv = *(const float2*)(w + t * 2);
    float2 bv = *(const float2*)(b + t * 2);
    const float zn0 = (xv.x - mu) * inv * wv.x + bv.x;
    const float zn1 = (xv.y - mu) * inv * wv.y + bv.y;
    float ph[NHEAD];
#pragma unroll
    for (int h = 0; h < NHEAD; h++)
        ph[h] = zn0 * Wz[(2 * t) * NHEAD + h] + zn1 * Wz[(2 * t + 1) * NHEAD + h];
#pragma unroll
    for (int h = 0; h < NHEAD; h++) {
#pragma unroll
        for (int off = 32; off > 0; off >>= 1) ph[h] += __shfl_xor(ph[h], off);
    }
    if (t == 0) {
#pragma unroll
        for (int h = 0; h < NHEAD; h++)
            bias[(size_t)h * NROW + pair] = ph[h] * 1.4426950408889634f;  // log2(e) folded
    }
}

// ---------------- weight transpose: all -> single bf16 Bt[n][k] ----------------
__global__ void __launch_bounds__(256)
wsplit_kernel(const float* __restrict__ Wq, const float* __restrict__ Wk,
              const float* __restrict__ Wv, const float* __restrict__ Wg,
              const float* __restrict__ Wo, unsigned short* __restrict__ wbf) {
    const int n = blockIdx.x;        // output row (col of W)
    const int mat = blockIdx.y;      // 0..4
    const int k = threadIdx.x;       // 0..255
    const float* W = (mat == 0) ? Wq : (mat == 1) ? Wk : (mat == 2) ? Wv
                   : (mat == 3) ? Wg : Wo;
    const float v = W[(size_t)k * 256 + n];
    unsigned short* hi = wbf + (size_t)mat * 65536;
    hi[(size_t)n * 256 + k] = f2bf(v);
}

// fused Q/K/V/G projection: BK=64, XOR-swizzled LDS (bank-conflict-free),
// LDS-staged vectorized head-major epilogue.
__global__ void __launch_bounds__(256)
gemm_qkvg_kernel(const unsigned short* __restrict__ A,
                 const unsigned short* __restrict__ wbf,
                 unsigned short* __restrict__ qb, unsigned short* __restrict__ kb,
                 unsigned short* __restrict__ vb, unsigned short* __restrict__ gb,
                 const float* __restrict__ bg, float scale, int rowsTot) {
    __shared__ short LDS[128 * 128];          // 32 KB: A=[0,8K), B=[8K,16K) shorts
    short* A_s = LDS;
    short* B_s = LDS + 128 * 64;
    int bx, by;
    xcd_remap(bx, by);
    const int which = bx >> 1;
    const int n0 = (bx & 1) * 128;
    const int m0 = by * 128;
    const unsigned short* Bt_g = wbf + (size_t)which * 65536;
    unsigned short* C = (which == 0) ? qb : (which == 1) ? kb : (which == 2) ? vb : gb;
    const float alpha = (which == 0) ? scale : 1.0f;
    const float* bias = (which == 3) ? bg : nullptr;
    const int act = (which == 3) ? 1 : 0;

    const int tid  = threadIdx.x;
    const int wid  = tid >> 6;
    const int lane = tid & 63;
    const int wm = (wid >> 1) * 64;
    const int wn = (wid & 1) * 64;

    f32x4 acc[4][4];
#pragma unroll
    for (int i = 0; i < 4; i++)
#pragma unroll
        for (int j = 0; j < 4; j++) acc[i][j] = (f32x4){0.f, 0.f, 0.f, 0.f};

    // staging: waves 0,1 -> A halves; waves 2,3 -> B halves. Row = 128 B (8 slots
    // of 16 B). Physical slot = logical ^ (row&7); dest linear, SOURCE pre-swizzled.
    const unsigned short* gmat = (wid < 2) ? A : Bt_g;
    short* lmat = (wid < 2) ? A_s : B_s;
    const int brow = (wid < 2) ? m0 : n0;
    const int half = (wid & 1) * 64;
    const int srow  = lane >> 3;                  // 0..7 row within 8-row group
    const int sslot = (lane & 7) ^ srow;          // pre-swizzled logical slot

    const int lrow = lane & 15;
    const int lg   = lane >> 4;
    // read-side physical slots (elem offsets) for the two 32-k chunks
    const int x0 = ((0 + lg) ^ (lane & 7)) * 8;
    const int x1 = ((4 + lg) ^ (lane & 7)) * 8;

    for (int k0 = 0; k0 < 256; k0 += 64) {
#pragma unroll
        for (int r = 0; r < 8; r++) {
            const unsigned short* g = gmat
                + (size_t)(brow + half + r * 8 + srow) * 256 + k0 + sslot * 8;
            short* l = lmat + (half + r * 8) * 64;   // HW adds lane*16B
            async16(g, l);
        }
        __syncthreads();   // drains vmcnt -> tiles complete

#pragma unroll
        for (int kk = 0; kk < 2; kk++) {
            const int x = kk ? x1 : x0;
            short8 af[4], bf[4];
#pragma unroll
            for (int f = 0; f < 4; f++) {
                af[f] = *(const short8*)&A_s[(wm + f * 16 + lrow) * 64 + x];
                bf[f] = *(const short8*)&B_s[(wn + f * 16 + lrow) * 64 + x];
            }
#pragma unroll
            for (int i = 0; i < 4; i++)
#pragma unroll
                for (int j = 0; j < 4; j++)
                    acc[i][j] = __builtin_amdgcn_mfma_f32_16x16x32_bf16(af[i], bf[j], acc[i][j], 0, 0, 0);
        }
        __syncthreads();   // safe to re-stage
    }

    // ---- epilogue: acc -> LDS (bf16 C tile), then vectorized head-major stores ----
    {
        const int ccol0 = lane & 15;
        const int crow0 = lg * 4;
        float bvv[4];
#pragma unroll
        for (int j = 0; j < 4; j++)
            bvv[j] = bias ? bias[n0 + wn + j * 16 + ccol0] : 0.0f;
#pragma unroll
        for (int i = 0; i < 4; i++)
#pragma unroll
            for (int r = 0; r < 4; r++) {
                const int row = wm + i * 16 + crow0 + r;
#pragma unroll
                for (int j = 0; j < 4; j++) {
                    float vv = acc[i][j][r] * alpha + bvv[j];
                    if (act == 1) vv = 1.0f / (1.0f + __expf(-vv));
                    LDS[row * 128 + wn + j * 16 + ccol0] = (short)f2bf(vv);
                }
            }
        __syncthreads();
        // stream out: tile row-major -> head-major planes, 16B/lane fully coalesced
        const int rr = tid >> 4;            // row within 16-row group
        const int cb = (tid & 15) * 8;      // col elem base
        const int pl = n0 / 32 + (cb >> 5); // head plane
        const int cw = cb & 31;
#pragma unroll
        for (int t = 0; t < 8; t++) {
            const int row = t * 16 + rr;
            short8 vv = *(const short8*)&LDS[row * 128 + cb];
            *(short8*)&C[((size_t)pl * rowsTot + m0 + row) * 32 + cw] = vv;
        }
    }
}

// output projection: C = (g*o) @ Wo + bo. A = single bf16 HEAD-MAJOR planes.
// Same BK=64 XOR-swizzled single-pass structure as gemm_qkvg.
__global__ void __launch_bounds__(256)
gemm_out_kernel(const unsigned short* __restrict__ A,
                const unsigned short* __restrict__ wbf, float* __restrict__ C,
                const float* __restrict__ bo, int rowsTot) {
    __shared__ short LDS[128 * 128];          // 32 KB
    short* A_s = LDS;
    short* B_s = LDS + 128 * 64;
    int bx, by;
    xcd_remap(bx, by);
    const int m0 = by * 128, n0 = bx * 128;
    const unsigned short* Bt_g = wbf + (size_t)4 * 65536;

    const int tid  = threadIdx.x;
    const int wid  = tid >> 6;
    const int lane = tid & 63;
    const int wm = (wid >> 1) * 64;
    const int wn = (wid & 1) * 64;

    f32x4 acc[4][4];
#pragma unroll
    for (int i = 0; i < 4; i++)
#pragma unroll
        for (int j = 0; j < 4; j++) acc[i][j] = (f32x4){0.f, 0.f, 0.f, 0.f};

    const int half = (wid & 1) * 64;
    const int srow  = lane >> 3;
    const int sslot = (lane & 7) ^ srow;

    const int lrow = lane & 15;
    const int lg   = lane >> 4;
    const int x0 = ((0 + lg) ^ (lane & 7)) * 8;
    const int x1 = ((4 + lg) ^ (lane & 7)) * 8;

    for (int k0 = 0; k0 < 256; k0 += 64) {
#pragma unroll
        for (int r = 0; r < 8; r++) {
            if (wid < 2) {
                // A head-major: logical slot s -> plane (k0>>5)+(s>>2), col (s&3)*8
                const int row = m0 + half + r * 8 + srow;
                const unsigned short* g = A
                    + ((size_t)((k0 >> 5) + (sslot >> 2)) * rowsTot + row) * 32
                    + (sslot & 3) * 8;
                short* l = A_s + (half + r * 8) * 64;
                async16(g, l);
            } else {
                const unsigned short* g = Bt_g
                    + (size_t)(n0 + half + r * 8 + srow) * 256 + k0 + sslot * 8;
                short* l = B_s + (half + r * 8) * 64;
                async16(g, l);
            }
        }
        __syncthreads();

#pragma unroll
        for (int kk = 0; kk < 2; kk++) {
            const int x = kk ? x1 : x0;
            short8 af[4], bf[4];
#pragma unroll
            for (int f = 0; f < 4; f++) {
                af[f] = *(const short8*)&A_s[(wm + f * 16 + lrow) * 64 + x];
                bf[f] = *(const short8*)&B_s[(wn + f * 16 + lrow) * 64 + x];
            }
#pragma unroll
            for (int i = 0; i < 4; i++)
#pragma unroll
                for (int j = 0; j < 4; j++)
                    acc[i][j] = __builtin_amdgcn_mfma_f32_16x16x32_bf16(af[i], bf[j], acc[i][j], 0, 0, 0);
        }
        __syncthreads();
    }

    const int ccol0 = lane & 15;
    const int crow0 = lg * 4;
    float bvv[4];
#pragma unroll
    for (int j = 0; j < 4; j++)
        bvv[j] = bo[n0 + wn + j * 16 + ccol0];
#pragma unroll
    for (int i = 0; i < 4; i++) {
#pragma unroll
        for (int r = 0; r < 4; r++) {
            const int row = m0 + wm + i * 16 + crow0 + r;
#pragma unroll
            for (int j = 0; j < 4; j++) {
                const int col = n0 + wn + j * 16 + ccol0;
                C[(size_t)row * 256 + col] = acc[i][j][r] + bvv[j];
            }
        }
    }
}

// ---------------- MFMA attention: block=(s,h), 4 waves x 64 q-rows ----------------
// Bias PREFETCHED into registers (double-buffered half-chunks) -> the global
// float4 load leaves the critical path. Output single bf16 head-major.
#define ISSUE_B(DST, KABS) do {                                              \
    const int ka_ = (KABS);                                                  \
    _Pragma("unroll")                                                        \
    for (int jq_ = 0; jq_ < 4; jq_++)                                        \
        DST[jq_] = *(const float4*)(bh + (size_t)(wq0 + jq_ * 16 + l15) * NRES + ka_); \
} while (0)

#define PROCESS_IK(KB, IK, BB) do {                                          \
    const int kb_ = (KB), ik_ = (IK);                                        \
    short8 kf_ = *(const short8*)&Ks[kb_ + ik_ * 16 + l15][lg * 8];          \
    s16x4 vf0_ = *(const s16x4*)&Vs[l15][kb_ + ik_ * 16 + lg * 4];           \
    s16x4 vf1_ = *(const s16x4*)&Vs[16 + l15][kb_ + ik_ * 16 + lg * 4];      \
    _Pragma("unroll")                                                        \
    for (int jq_ = 0; jq_ < 4; jq_++) {                                      \
        f32x4 sa_ = (f32x4){0.f, 0.f, 0.f, 0.f};                             \
        sa_ = __builtin_amdgcn_mfma_f32_16x16x32_bf16(kf_, qf[jq_], sa_, 0, 0, 0); \
        const float p0_ = __builtin_amdgcn_exp2f(sa_[0] + BB[jq_].x);        \
        const float p1_ = __builtin_amdgcn_exp2f(sa_[1] + BB[jq_].y);        \
        const float p2_ = __builtin_amdgcn_exp2f(sa_[2] + BB[jq_].z);        \
        const float p3_ = __builtin_amdgcn_exp2f(sa_[3] + BB[jq_].w);        \
        lip[jq_] += (p0_ + p1_) + (p2_ + p3_);                               \
        s16x4 pa_;                                                           \
        pa_[0] = (short)f2bf(p0_); pa_[1] = (short)f2bf(p1_);                \
        pa_[2] = (short)f2bf(p2_); pa_[3] = (short)f2bf(p3_);                \
        acco[jq_][0] = __builtin_amdgcn_mfma_f32_16x16x16bf16_1k(pa_, vf0_, acco[jq_][0], 0, 0, 0); \
        acco[jq_][1] = __builtin_amdgcn_mfma_f32_16x16x16bf16_1k(pa_, vf1_, acco[jq_][1], 0, 0, 0); \
    }                                                                        \
} while (0)

__global__ void __launch_bounds__(256, 4)
attn_mfma_kernel(const unsigned short* __restrict__ q, const unsigned short* __restrict__ k,
                 const unsigned short* __restrict__ v, const float* __restrict__ bias_qk,
                 const unsigned short* __restrict__ g,
                 unsigned short* __restrict__ obf, int rows) {
    const int s = blockIdx.x, h = blockIdx.y;
    __shared__ short Ks[256][40];    // K bf16 [kk][c]            20480 B
    __shared__ short Vs[32][268];    // V^T bf16 [c][kk]          17152 B
    __shared__ float li_s[4][64];    //                             1024 B  => 38656 B
    const int tid = threadIdx.x;
    const int w = tid >> 6, l = tid & 63;
    const int lg = l >> 4, l15 = l & 15;
    const size_t hb = ((size_t)h * rows + (size_t)s * NRES) * 32;  // head-major base

    // ---- stage K (row-major) and V (transposed); fully coalesced contiguous reads ----
    {
        const int kk0 = tid >> 2;          // 0..63
        const int c8 = (tid & 3) * 8;      // 0,8,16,24
#pragma unroll
        for (int r4 = 0; r4 < 4; r4++) {
            const int kk = r4 * 64 + kk0;
            const size_t gi = hb + (size_t)kk * 32 + c8;
            short8 k8 = *(const short8*)(k + gi);
            short8 v8 = *(const short8*)(v + gi);
            *(short8*)&Ks[kk][c8] = k8;
#pragma unroll
            for (int jj = 0; jj < 8; jj++) Vs[c8 + jj][kk] = v8[jj];
        }
    }
    // ---- Q fragments straight from global bf16 (B-operand: col=l15, k=lg*8..+8) ----
    const int wq0 = w * 64;
    short8 qf[4];
#pragma unroll
    for (int mq = 0; mq < 4; mq++)
        qf[mq] = *(const short8*)(q + hb + (size_t)(wq0 + mq * 16 + l15) * 32 + lg * 8);
    __syncthreads();

    f32x4 acco[4][2];
#pragma unroll
    for (int mq = 0; mq < 4; mq++)
#pragma unroll
        for (int nc = 0; nc < 2; nc++) acco[mq][nc] = (f32x4){0.f, 0.f, 0.f, 0.f};
    float lip[4] = {0.f, 0.f, 0.f, 0.f};
    const float* bh = bias_qk + (size_t)h * NROW;

    // ---- K-loop with bias register double-buffering ----
    float4 bb0[4], bb1[4];
    ISSUE_B(bb0, lg * 4);                        // ch=0, ik=0
    for (int ch = 0; ch < 8; ch++) {
        const int kb = ch * 32;
        ISSUE_B(bb1, kb + 16 + lg * 4);          // this ch, ik=1
        PROCESS_IK(kb, 0, bb0);
        if (ch < 7) ISSUE_B(bb0, kb + 32 + lg * 4);  // next ch, ik=0
        PROCESS_IK(kb, 1, bb1);
    }

    // ---- row-sum reduction across lane groups; remap via tiny LDS ----
#pragma unroll
    for (int jq = 0; jq < 4; jq++) {
        lip[jq] += __shfl_xor(lip[jq], 16);
        lip[jq] += __shfl_xor(lip[jq], 32);
        li_s[w][jq * 16 + l15] = lip[jq];
    }

    // ---- epilogue: O/li * g, single bf16 head-major stores ----
#pragma unroll
    for (int mq = 0; mq < 4; mq++) {
#pragma unroll
        for (int r = 0; r < 4; r++) {
            const int qrow = wq0 + mq * 16 + lg * 4 + r;
            const float inv = 1.0f / li_s[w][mq * 16 + lg * 4 + r];
            const size_t rb = hb + (size_t)qrow * 32;
#pragma unroll
            for (int nc = 0; nc < 2; nc++) {
                const int c = nc * 16 + l15;
                const float val = acco[mq][nc][r] * inv * bf2f(g[rb + c]);
                obf[rb + c] = f2bf(val);
            }
        }
    }
}

extern "C" void kernel_launch(void* const* d_in, const int* in_sizes, int n_in,
                              void* d_out, int out_size, void* d_ws, size_t ws_size,
                              hipStream_t stream) {
    const float* m    = (const float*)d_in[0];
    const float* z    = (const float*)d_in[1];
    const float* lnmw = (const float*)d_in[2];
    const float* lnmb = (const float*)d_in[3];
    const float* lnzw = (const float*)d_in[4];
    const float* lnzb = (const float*)d_in[5];
    const float* Wz   = (const float*)d_in[6];
    const float* Wq   = (const float*)d_in[7];
    const float* Wk   = (const float*)d_in[8];
    const float* Wv   = (const float*)d_in[9];
    const float* Wg   = (const float*)d_in[10];
    const float* bg   = (const float*)d_in[11];
    const float* Wo   = (const float*)d_in[12];
    const float* bo   = (const float*)d_in[13];
    float* out = (float*)d_out;

    char* wsb = (char*)d_ws;
    const size_t BIASB = (size_t)NHEAD * NROW * 4;   // 2 MB
    const size_t WBFB  = (size_t)5 * 65536 * 2;      // 640 KB
    float* bias_qk = (float*)wsb;
    unsigned short* wbf = (unsigned short*)(wsb + BIASB);
    char* chunk0 = wsb + BIASB + ((WBFB + 255) & ~(size_t)255);

    // Per-s-elem: q,k,v,g,mbf,obf bf16 = 12 B
    const size_t avail = ws_size - (size_t)(chunk0 - wsb);
    int SC = NSEQ;
    while (SC > 1 && (size_t)SC * NRES * CM * 12 > avail) SC >>= 1;
    const size_t CHE = (size_t)SC * NRES * CM;

    unsigned short* qb  = (unsigned short*)chunk0;
    unsigned short* kb  = qb + CHE;
    unsigned short* vb  = kb + CHE;
    unsigned short* gb  = vb + CHE;
    unsigned short* mbf = gb + CHE;
    unsigned short* obf = mbf + CHE;

    ln_z_bias_kernel<<<NROW, 64, 0, stream>>>(z, lnzw, lnzb, Wz, bias_qk);
    wsplit_kernel<<<dim3(256, 5), 256, 0, stream>>>(Wq, Wk, Wv, Wg, Wo, wbf);

    const int rows = SC * NRES;
    const int mtiles = rows / 128;
    // scale * log2(e): softmax runs in exp2 domain
    const float scale = 0.17677669529663687f * 1.4426950408889634f;

    for (int s0 = 0; s0 < NSEQ; s0 += SC) {
        const float* m_c   = m   + (size_t)s0 * NRES * CM;
        float*       out_c = out + (size_t)s0 * NRES * CM;

        ln_m_kernel<<<rows, 64, 0, stream>>>(m_c, lnmw, lnmb, mbf);

        gemm_qkvg_kernel<<<dim3(8, mtiles), 256, 0, stream>>>(
            mbf, wbf, qb, kb, vb, gb, bg, scale, rows);

        attn_mfma_kernel<<<dim3(SC, NHEAD), 256, 0, stream>>>(
            qb, kb, vb, bias_qk, gb, obf, rows);

        gemm_out_kernel<<<dim3(2, mtiles), 256, 0, stream>>>(
            obf, wbf, out_c, bo, rows);
    }
}